// Round 17
// baseline (275.501 us; speedup 1.0000x reference)
//
#include <hip/hip_runtime.h>
#include <math.h>

namespace {

constexpr int nB = 8, nT = 512, nD = 1024, nH = 8, nDK = 128, nDV = 128, nC = 512, nM = 512;
constexpr int NROW = nB * nT;                  // 4096
constexpr float RTAU = 0.08838834764831845f;   // 1/sqrt(128)

typedef __attribute__((ext_vector_type(8))) short short8;
typedef __attribute__((ext_vector_type(4))) float f32x4;

__device__ __forceinline__ ushort f2bf(float f) {
  union { float f; uint u; } x; x.f = f;
  uint r = x.u + 0x7fff + ((x.u >> 16) & 1);
  return (ushort)(r >> 16);
}
__device__ __forceinline__ uint pk2(float a, float b) {
  return (uint)f2bf(a) | ((uint)f2bf(b) << 16);
}
__device__ __forceinline__ float bf2f(ushort u) {
  return __uint_as_float(((uint)u) << 16);
}
__device__ __forceinline__ void gload16(const void* g, void* l) {
  __builtin_amdgcn_global_load_lds((const __attribute__((address_space(1))) void*)g,
                                   (__attribute__((address_space(3))) void*)l, 16, 0, 0);
}
__device__ __forceinline__ void gload4(const void* g, void* l) {
  __builtin_amdgcn_global_load_lds((const __attribute__((address_space(1))) void*)g,
                                   (__attribute__((address_space(3))) void*)l, 4, 0, 0);
}

// ---------------- fused prep: ln | xlk cast | xlvT | aggUT | wtrans x5 | cbprep ----------------
constexpr int PREP_LN = 4096;
constexpr int PREP_XLK = PREP_LN + 4096;       // 8192
constexpr int PREP_XLVT = PREP_XLK + 1024;     // 9216
constexpr int PREP_AGGUT = PREP_XLVT + 1024;   // 10240
constexpr int PREP_WT = PREP_AGGUT + 1280;     // 11520
constexpr int PREP_TOTAL = PREP_WT + 2048;     // 13568

__global__ __launch_bounds__(256) void prep_kernel(
    const float* __restrict__ x, const float* __restrict__ gw, const float* __restrict__ bw,
    ushort* __restrict__ xt_bf,
    const float* __restrict__ xlk, ushort* __restrict__ xlk_bf,
    const float* __restrict__ xlv, ushort* __restrict__ xlvT,
    const float* __restrict__ aggU, ushort* __restrict__ aggUT,
    const float* __restrict__ wq, const float* __restrict__ wk, const float* __restrict__ wv,
    const float* __restrict__ wg, const float* __restrict__ wres,
    ushort* __restrict__ wqkvg_t, ushort* __restrict__ wres_t,
    const float* __restrict__ cb, float* __restrict__ cbn, ushort* __restrict__ cb_bf) {
  __shared__ float tile[64][65];
  __shared__ float smc[4];
  const int bid = blockIdx.x;
  const int tid = threadIdx.x;

  if (bid < PREP_LN) {
    size_t row = bid;
    float4 v = ((const float4*)(x + row * nD))[tid];
    {
      int lane = tid & 63, w = tid >> 6;
      float s = v.x + v.y + v.z + v.w;
#pragma unroll
      for (int off = 32; off; off >>= 1) s += __shfl_down(s, off);
      if (lane == 0) smc[w] = s;
    }
    __syncthreads();
    float mu = (smc[0] + smc[1] + smc[2] + smc[3]) * (1.f / nD);
    __syncthreads();
    float4 d = make_float4(v.x - mu, v.y - mu, v.z - mu, v.w - mu);
    {
      int lane = tid & 63, w = tid >> 6;
      float s = d.x * d.x + d.y * d.y + d.z * d.z + d.w * d.w;
#pragma unroll
      for (int off = 32; off; off >>= 1) s += __shfl_down(s, off);
      if (lane == 0) smc[w] = s;
    }
    __syncthreads();
    float var = (smc[0] + smc[1] + smc[2] + smc[3]) * (1.f / nD);
    float rs = rsqrtf(var + 1e-6f);
    float4 gg = ((const float4*)gw)[tid];
    float4 bb = ((const float4*)bw)[tid];
    uint2 pb;
    pb.x = pk2(d.x * rs * gg.x + bb.x, d.y * rs * gg.y + bb.y);
    pb.y = pk2(d.z * rs * gg.z + bb.z, d.w * rs * gg.w + bb.w);
    ((uint2*)(xt_bf + row * nD))[tid] = pb;
  } else if (bid < PREP_XLK) {
    const int blk = bid - PREP_LN;
    size_t idx = (size_t)blk * 256 + tid;
    float4 v = ((const float4*)xlk)[idx];
    uint2 p;
    p.x = pk2(v.x, v.y);
    p.y = pk2(v.z, v.w);
    ((uint2*)xlk_bf)[idx] = p;
  } else if (bid < PREP_AGGUT) {
    // transpose-cast [bh][512][128] -> [bh][128][512]
    const bool isXlv = bid < PREP_XLVT;
    const int i = bid - (isXlv ? PREP_XLK : PREP_XLVT);
    const float* S = isXlv ? xlv : aggU;
    ushort* D = isXlv ? xlvT : aggUT;
    const int bh = i >> 4, t = i & 15;
    const int tok0 = (t >> 1) * 64, d0 = (t & 1) * 64;
    const float* src = S + ((size_t)bh * 512 + tok0) * 128 + d0;
    ushort* dst = D + ((size_t)bh * 128 + d0) * 512 + tok0;
    const int c = tid & 63, r4 = tid >> 6;
#pragma unroll
    for (int k = 0; k < 16; ++k) {
      int r = k * 4 + r4;
      tile[r][c] = src[(size_t)r * 128 + c];
    }
    __syncthreads();
#pragma unroll
    for (int k = 0; k < 16; ++k) {
      int dd = k * 4 + r4;
      dst[(size_t)dd * 512 + c] = f2bf(tile[c][dd]);
    }
  } else if (bid < PREP_WT) {
    const int i = bid - PREP_AGGUT;
    const int z = i >> 8, rem = i & 255;
    const int kz = (rem >> 4) * 64, nz = (rem & 15) * 64;
    const float* W;
    ushort* D;
    if (z == 0)      { W = wq;   D = wqkvg_t; }
    else if (z == 1) { W = wk;   D = wqkvg_t + (size_t)1024 * 1024; }
    else if (z == 2) { W = wv;   D = wqkvg_t + (size_t)2048 * 1024; }
    else if (z == 3) { W = wg;   D = wqkvg_t + (size_t)3072 * 1024; }
    else             { W = wres; D = wres_t; }
    const int c = tid & 63, r4 = tid >> 6;
#pragma unroll
    for (int k = 0; k < 16; ++k) {
      int r = k * 4 + r4;
      tile[r][c] = W[(size_t)(kz + r) * 1024 + nz + c];
    }
    __syncthreads();
#pragma unroll
    for (int k = 0; k < 16; ++k) {
      int n = k * 4 + r4;
      D[(size_t)(nz + n) * 1024 + kz + c] = f2bf(tile[c][n]);
    }
  } else {
    const int i = bid - PREP_WT;
    const int grp = tid >> 7, t128 = tid & 127;
    const int hc = i * 2 + grp;
    float v = cb[(size_t)hc * 128 + t128];
    cb_bf[(size_t)hc * 128 + t128] = f2bf(v);
    float s = v * v;
#pragma unroll
    for (int off = 32; off; off >>= 1) s += __shfl_down(s, off);
    if ((t128 & 63) == 0) smc[grp * 2 + (t128 >> 6)] = s;
    __syncthreads();
    if (t128 == 0) cbn[hc] = smc[grp * 2] + smc[grp * 2 + 1];
  }
}

// ---------------- bf16 MFMA GEMM (128x128 tile, BK=32) ----------------
// MODE 0: fp32 -> C0.
// MODE 1: seg0 q -> hln+xu -> C1 bf16; seg1 k -> hln -> kbf bf16 + knorm2;
//         seg2 v -> LDS-transpose -> vT[b][h][d][token] bf16 (C2); seg3 silu -> C3 bf16.
template <int MODE>
__global__ __launch_bounds__(256) void gemm_bf16_kernel(const ushort* __restrict__ A,
                                                        const ushort* __restrict__ Bt,
                                                        float* __restrict__ C0,
                                                        ushort* __restrict__ C1,
                                                        ushort* __restrict__ C2,
                                                        ushort* __restrict__ C3,
                                                        ushort* __restrict__ kbf,
                                                        float* __restrict__ knorm2,
                                                        const float* __restrict__ xu) {
  __shared__ __align__(16) ushort As[128 * 32];
  __shared__ __align__(16) ushort Bs[128 * 32];
  __shared__ float rowsum[128][2];
  __shared__ float rowsum2[128][2];
  __shared__ __align__(16) ushort tbuf[128][72];
  const int tid = threadIdx.x;
  const int w = tid >> 6, l = tid & 63;
  const int lr = l & 15, lg = l >> 4;
  const int wr = w >> 1, wc = w & 1;
  const int n0 = blockIdx.x * 128;
  const int m0 = blockIdx.y * 128;
  constexpr int K = 1024;

  f32x4 acc[4][4];
#pragma unroll
  for (int i = 0; i < 4; ++i)
#pragma unroll
    for (int j = 0; j < 4; ++j) acc[i][j] = (f32x4){0.f, 0.f, 0.f, 0.f};

  const int e0 = w * 512 + l * 8;
  const int r0 = e0 >> 5, c0 = e0 & 31;
  const int e1 = 2048 + e0;
  const int r1 = e1 >> 5, c1 = e1 & 31;
  const ushort* a0p = A + (size_t)(m0 + r0) * K + c0;
  const ushort* a1p = A + (size_t)(m0 + r1) * K + c1;
  const ushort* b0p = Bt + (size_t)(n0 + r0) * K + c0;
  const ushort* b1p = Bt + (size_t)(n0 + r1) * K + c1;
  ushort* lA0 = &As[w * 512];
  ushort* lA1 = &As[2048 + w * 512];
  ushort* lB0 = &Bs[w * 512];
  ushort* lB1 = &Bs[2048 + w * 512];

  for (int k0 = 0; k0 < K; k0 += 32) {
    __syncthreads();
    gload16(a0p + k0, lA0);
    gload16(a1p + k0, lA1);
    gload16(b0p + k0, lB0);
    gload16(b1p + k0, lB1);
    __syncthreads();
    short8 af[4], bfr[4];
#pragma unroll
    for (int i = 0; i < 4; ++i) af[i] = *(const short8*)&As[(wr * 64 + i * 16 + lr) * 32 + lg * 8];
#pragma unroll
    for (int j = 0; j < 4; ++j) bfr[j] = *(const short8*)&Bs[(wc * 64 + j * 16 + lr) * 32 + lg * 8];
    __builtin_amdgcn_s_setprio(1);
#pragma unroll
    for (int i = 0; i < 4; ++i)
#pragma unroll
      for (int j = 0; j < 4; ++j)
        acc[i][j] = __builtin_amdgcn_mfma_f32_16x16x32_bf16(af[i], bfr[j], acc[i][j], 0, 0, 0);
    __builtin_amdgcn_s_setprio(0);
  }

  const int seg = n0 >> 10;
  const int nbase = n0 & 1023;
  if (MODE == 1 && seg <= 1) {
    const int h = nbase >> 7;
    float ps[4][4], ps2[4][4];
#pragma unroll
    for (int i = 0; i < 4; ++i)
#pragma unroll
      for (int r2 = 0; r2 < 4; ++r2) {
        float s = 0.f, s2 = 0.f;
#pragma unroll
        for (int j = 0; j < 4; ++j) {
          float v = acc[i][j][r2];
          s += v;
          s2 += v * v;
        }
#pragma unroll
        for (int off = 1; off < 16; off <<= 1) {
          s += __shfl_xor(s, off);
          s2 += __shfl_xor(s2, off);
        }
        ps[i][r2] = s;
        ps2[i][r2] = s2;
      }
    if (lr == 0) {
#pragma unroll
      for (int i = 0; i < 4; ++i)
#pragma unroll
        for (int r2 = 0; r2 < 4; ++r2) {
          int rloc = wr * 64 + i * 16 + lg * 4 + r2;
          rowsum[rloc][wc] = ps[i][r2];
          rowsum2[rloc][wc] = ps2[i][r2];
        }
    }
    __syncthreads();
#pragma unroll
    for (int i = 0; i < 4; ++i)
#pragma unroll
      for (int r2 = 0; r2 < 4; ++r2) {
        const int rloc = wr * 64 + i * 16 + lg * 4 + r2;
        const int grow = m0 + rloc;
        float tot = rowsum[rloc][0] + rowsum[rloc][1];
        float tot2 = rowsum2[rloc][0] + rowsum2[rloc][1];
        float mu = tot * (1.f / 128.f);
        float qf = tot2 - 128.f * mu * mu;
        float rs = rsqrtf(qf * (1.f / 128.f) + 1e-6f);
#pragma unroll
        for (int j = 0; j < 4; ++j) {
          const int col = wc * 64 + j * 16 + lr;
          float v = (acc[i][j][r2] - mu) * rs;
          if (seg == 0) {
            v += xu[h * 128 + col];
            C1[(size_t)grow * 1024 + nbase + col] = f2bf(v);
          } else {
            kbf[(size_t)grow * 1024 + nbase + col] = f2bf(v);
          }
        }
        if (seg == 1 && lr == 0 && wc == 0) knorm2[(size_t)grow * 8 + h] = qf * rs * rs;
      }
  } else if (MODE == 1 && seg == 2) {
    // v: LDS transpose -> vT[b][h][d][token]
    const int h = nbase >> 7;
    const int bq = m0 >> 9;
    const int tokbase = m0 & 511;
#pragma unroll
    for (int half = 0; half < 2; ++half) {
      __syncthreads();
      if (wr == half) {
#pragma unroll
        for (int i = 0; i < 4; ++i)
#pragma unroll
          for (int j = 0; j < 4; ++j)
#pragma unroll
            for (int r2 = 0; r2 < 4; ++r2) {
              const int col = wc * 64 + j * 16 + lr;   // d
              const int rl = i * 16 + lg * 4 + r2;     // token local in half
              tbuf[col][rl] = f2bf(acc[i][j][r2]);
            }
      }
      __syncthreads();
      {
        const int d = tid >> 1;
        const int hrow = tid & 1;
        ushort* gdst = C2 + (((size_t)(bq * 8 + h) * 128 + d) * 512
                             + tokbase + half * 64 + hrow * 32);
        const ushort* lsrc = &tbuf[d][hrow * 32];
#pragma unroll
        for (int q = 0; q < 4; ++q)
          *(uint4*)(gdst + q * 8) = *(const uint4*)(lsrc + q * 8);
      }
    }
  } else {
#pragma unroll
    for (int i = 0; i < 4; ++i)
#pragma unroll
      for (int j = 0; j < 4; ++j)
#pragma unroll
        for (int r2 = 0; r2 < 4; ++r2) {
          const int row = m0 + wr * 64 + i * 16 + lg * 4 + r2;
          const int col = wc * 64 + j * 16 + lr;
          float v = acc[i][j][r2];
          if (MODE == 0) {
            C0[(size_t)row * 1024 + n0 + col] = v;
          } else {
            float s = v / (1.f + __expf(-v));
            C3[(size_t)row * 1024 + nbase + col] = f2bf(s);
          }
        }
  }
}

// ---------------- MFMA VQ: argmin over 512 codes via k.c MFMA ----------------
__global__ __launch_bounds__(256) void vq_mfma_kernel(const ushort* __restrict__ kbf,
                                                      const ushort* __restrict__ cb_bf,
                                                      const float* __restrict__ cbn,
                                                      const float* __restrict__ knorm2,
                                                      const float* __restrict__ mask,
                                                      ushort* __restrict__ khat_bf,
                                                      float* __restrict__ blocksq) {
  __shared__ ushort Kb[64][136];
  __shared__ ushort Cb[64][136];
  __shared__ float cnsh[64];
  __shared__ int zsh[64];
  __shared__ float dsh[64];
  const int tid = threadIdx.x;
  const int w = tid >> 6, l = tid & 63;
  const int lr = l & 15, lg = l >> 4;
  const int b = blockIdx.y >> 3, h = blockIdx.y & 7;
  const int t0 = blockIdx.x * 64;
  const int srow = tid >> 2, sd = (tid & 3) * 32;

  {
    const ushort* src = kbf + ((size_t)((b * nT + t0 + srow) * nH + h)) * 128 + sd;
    *(uint4*)&Kb[srow][sd] = *(const uint4*)src;
    *(uint4*)&Kb[srow][sd + 8] = *(const uint4*)(src + 8);
    *(uint4*)&Kb[srow][sd + 16] = *(const uint4*)(src + 16);
    *(uint4*)&Kb[srow][sd + 24] = *(const uint4*)(src + 24);
  }
  __syncthreads();

  short8 af[4];
#pragma unroll
  for (int k0 = 0; k0 < 4; ++k0) af[k0] = *(const short8*)&Kb[w * 16 + lr][k0 * 32 + lg * 8];

  float best[4] = {1e30f, 1e30f, 1e30f, 1e30f};
  int bidx[4] = {0, 0, 0, 0};

  for (int cc = 0; cc < 8; ++cc) {
    __syncthreads();
    {
      const ushort* src = cb_bf + ((size_t)(h * nC + cc * 64 + srow)) * 128 + sd;
      *(uint4*)&Cb[srow][sd] = *(const uint4*)src;
      *(uint4*)&Cb[srow][sd + 8] = *(const uint4*)(src + 8);
      *(uint4*)&Cb[srow][sd + 16] = *(const uint4*)(src + 16);
      *(uint4*)&Cb[srow][sd + 24] = *(const uint4*)(src + 24);
      if (tid < 64) cnsh[tid] = cbn[h * nC + cc * 64 + tid];
    }
    __syncthreads();
#pragma unroll
    for (int ct = 0; ct < 4; ++ct) {
      f32x4 z = (f32x4){0.f, 0.f, 0.f, 0.f};
#pragma unroll
      for (int k0 = 0; k0 < 4; ++k0) {
        short8 cf = *(const short8*)&Cb[ct * 16 + lr][k0 * 32 + lg * 8];
        z = __builtin_amdgcn_mfma_f32_16x16x32_bf16(af[k0], cf, z, 0, 0, 0);
      }
      const int code = cc * 64 + ct * 16 + lr;
      const float cn = cnsh[ct * 16 + lr];
#pragma unroll
      for (int r2 = 0; r2 < 4; ++r2) {
        float d = cn - 2.f * z[r2];
        if (d < best[r2]) { best[r2] = d; bidx[r2] = code; }
      }
    }
  }

#pragma unroll
  for (int off = 1; off < 16; off <<= 1) {
#pragma unroll
    for (int r2 = 0; r2 < 4; ++r2) {
      float od = __shfl_xor(best[r2], off);
      int oi = __shfl_xor(bidx[r2], off);
      if (od < best[r2] || (od == best[r2] && oi < bidx[r2])) { best[r2] = od; bidx[r2] = oi; }
    }
  }
  if (lr == 0) {
#pragma unroll
    for (int r2 = 0; r2 < 4; ++r2) {
      int row = w * 16 + lg * 4 + r2;
      zsh[row] = bidx[r2];
      dsh[row] = best[r2];
    }
  }
  __syncthreads();

  {
    const int row = tid >> 2, part = (tid & 3) * 32;
    const ushort* src = cb_bf + ((size_t)(h * nC + zsh[row])) * 128 + part;
    ushort* dst = khat_bf + ((size_t)((b * nT + t0 + row) * nH + h)) * 128 + part;
    *(uint4*)dst = *(const uint4*)src;
    *(uint4*)(dst + 8) = *(const uint4*)(src + 8);
    *(uint4*)(dst + 16) = *(const uint4*)(src + 16);
    *(uint4*)(dst + 24) = *(const uint4*)(src + 24);
  }

  if (tid < 64) {
    float s = mask[b * nT + t0 + tid] *
              (knorm2[(size_t)(b * nT + t0 + tid) * nH + h] + dsh[tid]);
#pragma unroll
    for (int off = 32; off; off >>= 1) s += __shfl_down(s, off);
    if (tid == 0) blocksq[blockIdx.y * gridDim.x + blockIdx.x] = s;
  }
}

// ---------------- MFMA flash attention: async 2-phase via gload_lds ping-pong ----------------
// grid = (bh, t0/64): linear id % 8 = h -> same-(b,h) blocks on one XCD (L2 share).
// K staged row-major [64][128], V staged d-major [128][64] (from pre-transposed vT globals),
// both with XOR swizzle byte^=((row&7)<<4) applied at SOURCE (gload is linear-dest) and READ.
__global__ __launch_bounds__(256) void attn_mfma_kernel(
    const ushort* __restrict__ qb, const ushort* __restrict__ khat,
    const ushort* __restrict__ vbufT, const ushort* __restrict__ xlk,
    const ushort* __restrict__ xlvT, const ushort* __restrict__ cbb,
    const ushort* __restrict__ aggUT, const float* __restrict__ aggL,
    const ushort* __restrict__ gbuf, ushort* __restrict__ o) {
  __shared__ __align__(16) ushort Ks[2][64][128];
  __shared__ __align__(16) ushort Vts[2][128][64];
  __shared__ ushort Ps[4][16][72];
  __shared__ float lowb[2][64];

  const int tid = threadIdx.x;
  const int w = tid >> 6, l = tid & 63;
  const int lr = l & 15, lg = l >> 4;
  const int b = blockIdx.x >> 3, h = blockIdx.x & 7;
  const int t0 = blockIdx.y * 64;

  short8 qf[4];
  {
    const ushort* qrow = qb + ((size_t)((b * nT + t0 + w * 16 + lr) * nH + h)) * 128;
#pragma unroll
    for (int k0 = 0; k0 < 4; ++k0) qf[k0] = *(const short8*)(qrow + k0 * 32 + lg * 8);
  }

  float m_r[4] = {-1e30f, -1e30f, -1e30f, -1e30f};
  float l_r[4] = {0.f, 0.f, 0.f, 0.f};
  f32x4 acc_o[8];
#pragma unroll
  for (int dt = 0; dt < 8; ++dt) acc_o[dt] = (f32x4){0.f, 0.f, 0.f, 0.f};

  const int nch = t0 / 64 + 9;
  const int ntot = nch + 8;

  auto stage = [&](int ci) {
    const int buf = ci & 1;
    const bool isAgg = ci >= nch;
    const int sb = isAgg ? (ci - nch) * 64 : ci * 64;
    char* kdst = (char*)&Ks[buf][0][0];
    char* vdst = (char*)&Vts[buf][0][0];
#pragma unroll
    for (int j = 0; j < 4; ++j) {
      {
        const int row = w * 16 + j * 4 + (l >> 4);
        const int scol = ((l & 15) * 16) ^ ((row & 7) << 4);
        const ushort* srow;
        if (isAgg) {
          srow = cbb + ((size_t)(h * nC + sb + row)) * 128;
        } else {
          const int s = sb + row;
          srow = (s < nM) ? xlk + ((size_t)(b * nH + h) * nM + s) * 128
                          : khat + ((size_t)((b * nT + (s - nM)) * nH + h)) * 128;
        }
        gload16((const char*)srow + scol, kdst + w * 4096 + j * 1024);
      }
      {
        const int d = w * 32 + j * 8 + (l >> 3);
        const int skb = ((l & 7) * 16) ^ ((d & 7) << 4);
        const ushort* srow;
        if (isAgg) {
          srow = aggUT + (((size_t)(b * nH + h) * 128 + d) * 512 + sb);
        } else if (sb < nM) {
          srow = xlvT + (((size_t)(b * nH + h) * 128 + d) * 512 + sb);
        } else {
          srow = vbufT + (((size_t)(b * nH + h) * 128 + d) * 512 + (sb - nM));
        }
        gload16((const char*)srow + skb, vdst + w * 4096 + j * 1024);
      }
    }
    if (isAgg && w == 0) {
      gload4(aggL + (size_t)(b * nH + h) * nC + sb + l, &lowb[buf][0]);
    }
  };

  auto chunk_body = [&](int ci) {
    const int buf = ci & 1;
    const bool AGG = ci >= nch;
    const bool MASKQ = ci == nch - 1;
    const int sbase = AGG ? 0 : ci * 64;   // sbase only used for mask (recent)
    const char* ksb = (const char*)&Ks[buf][0][0];
    const char* vsb = (const char*)&Vts[buf][0][0];
    f32x4 sc[4];
    __builtin_amdgcn_s_setprio(1);
#pragma unroll
    for (int kt = 0; kt < 4; ++kt) {
      f32x4 z = (f32x4){0.f, 0.f, 0.f, 0.f};
      const int R = kt * 16 + lr;
#pragma unroll
      for (int k0 = 0; k0 < 4; ++k0) {
        short8 kf = *(const short8*)(ksb + R * 256 + ((k0 * 64 + lg * 16) ^ ((R & 7) << 4)));
        z = __builtin_amdgcn_mfma_f32_16x16x32_bf16(qf[k0], kf, z, 0, 0, 0);
      }
      sc[kt] = z;
    }
    __builtin_amdgcn_s_setprio(0);
    float sv[4][4];
    float pm[4] = {-1e30f, -1e30f, -1e30f, -1e30f};
#pragma unroll
    for (int kt = 0; kt < 4; ++kt)
#pragma unroll
      for (int r2 = 0; r2 < 4; ++r2) {
        float s = sc[kt][r2] * RTAU;
        if (MASKQ) {
          int key = sbase + kt * 16 + lr;
          int tl = t0 + w * 16 + lg * 4 + r2 + nM;
          if (key > tl) s = -1e30f;
        }
        sv[kt][r2] = s;
        pm[r2] = fmaxf(pm[r2], s);
      }
#pragma unroll
    for (int r2 = 0; r2 < 4; ++r2)
#pragma unroll
      for (int off = 1; off < 16; off <<= 1) pm[r2] = fmaxf(pm[r2], __shfl_xor(pm[r2], off));
    float scale[4], rs[4];
#pragma unroll
    for (int r2 = 0; r2 < 4; ++r2) {
      float mn = fmaxf(m_r[r2], pm[r2]);
      scale[r2] = __expf(m_r[r2] - mn);
      m_r[r2] = mn;
      rs[r2] = 0.f;
    }
#pragma unroll
    for (int kt = 0; kt < 4; ++kt)
#pragma unroll
      for (int r2 = 0; r2 < 4; ++r2) {
        float p = __expf(sv[kt][r2] - m_r[r2]);
        rs[r2] += AGG ? p * lowb[buf][kt * 16 + lr] : p;
        Ps[w][lg * 4 + r2][kt * 16 + lr] = f2bf(p);
      }
#pragma unroll
    for (int r2 = 0; r2 < 4; ++r2)
#pragma unroll
      for (int off = 1; off < 16; off <<= 1) rs[r2] += __shfl_xor(rs[r2], off);
#pragma unroll
    for (int r2 = 0; r2 < 4; ++r2) l_r[r2] = l_r[r2] * scale[r2] + rs[r2];
#pragma unroll
    for (int dt = 0; dt < 8; ++dt)
#pragma unroll
      for (int r2 = 0; r2 < 4; ++r2) acc_o[dt][r2] *= scale[r2];
    short8 pa0 = *(const short8*)&Ps[w][lr][lg * 8];
    short8 pa1 = *(const short8*)&Ps[w][lr][32 + lg * 8];
    __builtin_amdgcn_s_setprio(1);
#pragma unroll
    for (int dt = 0; dt < 8; ++dt) {
      const int R2 = dt * 16 + lr;
      short8 vf0 = *(const short8*)(vsb + R2 * 128 + ((lg * 16) ^ ((R2 & 7) << 4)));
      short8 vf1 = *(const short8*)(vsb + R2 * 128 + ((64 + lg * 16) ^ ((R2 & 7) << 4)));
      acc_o[dt] = __builtin_amdgcn_mfma_f32_16x16x32_bf16(pa0, vf0, acc_o[dt], 0, 0, 0);
      acc_o[dt] = __builtin_amdgcn_mfma_f32_16x16x32_bf16(pa1, vf1, acc_o[dt], 0, 0, 0);
    }
    __builtin_amdgcn_s_setprio(0);
  };

  stage(0);
  __syncthreads();
  for (int ci = 0; ci < ntot; ++ci) {
    if (ci + 1 < ntot) stage(ci + 1);   // async into the other buffer
    chunk_body(ci);
    __syncthreads();                    // drains prefetch (had full compute to land)
  }

  float inv[4];
#pragma unroll
  for (int r2 = 0; r2 < 4; ++r2) inv[r2] = 1.f / l_r[r2];
#pragma unroll
  for (int dt = 0; dt < 8; ++dt)
#pragma unroll
    for (int r2 = 0; r2 < 4; ++r2) {
      int trow = t0 + w * 16 + lg * 4 + r2;
      size_t oi = ((size_t)(b * nT + trow)) * nD + h * 128 + dt * 16 + lr;
      float gv = bf2f(gbuf[oi]);
      o[oi] = f2bf(acc_o[dt][r2] * inv[r2] * gv);
    }
}

// ---------------- losses ----------------
__global__ __launch_bounds__(256) void finalize_kernel(const float* __restrict__ blocksq,
                                                       int nblk,
                                                       const float* __restrict__ mask,
                                                       float* __restrict__ outp) {
  __shared__ float sm[8];
  const int tid = threadIdx.x;
  float s = 0.f, ms = 0.f;
  for (int i = tid; i < NROW; i += 256) {
    if (i < nblk) s += blocksq[i];
    ms += mask[i];
  }
#pragma unroll
  for (int off = 32; off; off >>= 1) { s += __shfl_down(s, off); ms += __shfl_down(ms, off); }
  if ((tid & 63) == 0) { sm[tid >> 6] = s; sm[4 + (tid >> 6)] = ms; }
  __syncthreads();
  if (tid == 0) {
    float ts = sm[0] + sm[1] + sm[2] + sm[3];
    float tm = sm[4] + sm[5] + sm[6] + sm[7];
    float l = ts / (tm * (float)nH + 1e-6f);
    outp[0] = l;
    outp[1] = l;
  }
}

}  // namespace

extern "C" void kernel_launch(void* const* d_in, const int* in_sizes, int n_in,
                              void* d_out, int out_size, void* d_ws, size_t ws_size,
                              hipStream_t stream) {
  const float* x    = (const float*)d_in[0];
  const float* mask = (const float*)d_in[2];
  const float* xlk  = (const float*)d_in[3];
  const float* xlv  = (const float*)d_in[4];
  const float* aggU = (const float*)d_in[5];
  const float* aggL = (const float*)d_in[6];
  const float* wlng = (const float*)d_in[7];
  const float* wlnb = (const float*)d_in[8];
  const float* wq   = (const float*)d_in[9];
  const float* wk   = (const float*)d_in[10];
  const float* wv   = (const float*)d_in[11];
  const float* wg   = (const float*)d_in[12];
  const float* wres = (const float*)d_in[13];
  const float* xu   = (const float*)d_in[14];
  const float* cb   = (const float*)d_in[15];
  float* out = (float*)d_out;

  float* ws = (float*)d_ws;
  const size_t SZ = (size_t)NROW * nD;   // 4,194,304
  float*  kregion = ws;                                    // SZ floats: kbf
  ushort* qbuf_bf = (ushort*)(ws + SZ);                    // SZ ushorts
  ushort* khat_bf = (ushort*)(ws + SZ + SZ / 2);           // SZ ushorts
  ushort* vbufT   = (ushort*)(ws + 2 * SZ);                // SZ ushorts [b][h][d][tok]
  ushort* gbuf_bf = (ushort*)(ws + 2 * SZ + SZ / 2);       // SZ ushorts
  ushort* xt_bf   = (ushort*)(ws + 3 * SZ);                // SZ ushorts (obuf overlay)
  ushort* wqkvg_t = (ushort*)(ws + 3 * SZ + SZ / 2);       // SZ ushorts
  ushort* wres_t  = (ushort*)(ws + 4 * SZ);                // 1M ushorts
  ushort* xlk_bf  = (ushort*)(ws + 4 * SZ + SZ / 8);       // SZ ushorts
  ushort* xlvT    = (ushort*)(ws + 4 * SZ + SZ / 8 + SZ / 2);   // SZ ushorts
  ushort* aggUT   = (ushort*)(ws + 4 * SZ + SZ / 8 + SZ);       // SZ ushorts
  ushort* cb_bf   = (ushort*)(ws + 4 * SZ + SZ / 8 + 3 * SZ / 2);
  float*  cbn     = ws + 4 * SZ + SZ / 8 + 3 * SZ / 2 + SZ / 16;
  float*  knorm2  = cbn + 4096;
  float*  bsq     = knorm2 + 32768;
  ushort* kbf     = (ushort*)kregion;
  ushort* obuf_bf = xt_bf;

  prep_kernel<<<PREP_TOTAL, 256, 0, stream>>>(
      x, wlng, wlnb, xt_bf, xlk, xlk_bf, xlv, xlvT, aggU, aggUT,
      wq, wk, wv, wg, wres, wqkvg_t, wres_t, cb, cbn, cb_bf);

  gemm_bf16_kernel<1><<<dim3(32, 32), 256, 0, stream>>>(
      xt_bf, wqkvg_t, nullptr, qbuf_bf, vbufT, gbuf_bf, kbf, knorm2, xu);

  vq_mfma_kernel<<<dim3(nT / 64, nB * nH), 256, 0, stream>>>(kbf, cb_bf, cbn, knorm2,
                                                             mask, khat_bf, bsq);

  attn_mfma_kernel<<<dim3(nB * nH, nT / 64), 256, 0, stream>>>(
      qbuf_bf, khat_bf, vbufT, xlk_bf, xlvT, cb_bf, aggUT, aggL, gbuf_bf, obuf_bf);

  gemm_bf16_kernel<0><<<dim3(8, 32), 256, 0, stream>>>(
      obuf_bf, wres_t, out, nullptr, nullptr, nullptr, nullptr, nullptr, nullptr);
  finalize_kernel<<<1, 256, 0, stream>>>(bsq, nT / 64 * nB * nH, mask, out + SZ);
}

// Round 20
// 234.542 us; speedup vs baseline: 1.1746x; 1.1746x over previous
//
#include <hip/hip_runtime.h>
#include <math.h>

namespace {

constexpr int nB = 8, nT = 512, nD = 1024, nH = 8, nDK = 128, nDV = 128, nC = 512, nM = 512;
constexpr int NROW = nB * nT;                  // 4096
constexpr float RTAU = 0.08838834764831845f;   // 1/sqrt(128)

typedef __attribute__((ext_vector_type(8))) short short8;
typedef __attribute__((ext_vector_type(4))) float f32x4;

__device__ __forceinline__ ushort f2bf(float f) {
  union { float f; uint u; } x; x.f = f;
  uint r = x.u + 0x7fff + ((x.u >> 16) & 1);
  return (ushort)(r >> 16);
}
__device__ __forceinline__ uint pk2(float a, float b) {
  return (uint)f2bf(a) | ((uint)f2bf(b) << 16);
}
__device__ __forceinline__ float bf2f(ushort u) {
  return __uint_as_float(((uint)u) << 16);
}
__device__ __forceinline__ void gload16(const void* g, void* l) {
  __builtin_amdgcn_global_load_lds((const __attribute__((address_space(1))) void*)g,
                                   (__attribute__((address_space(3))) void*)l, 16, 0, 0);
}
__device__ __forceinline__ void gload4(const void* g, void* l) {
  __builtin_amdgcn_global_load_lds((const __attribute__((address_space(1))) void*)g,
                                   (__attribute__((address_space(3))) void*)l, 4, 0, 0);
}

// ---------------- fused prep: ln | xlk cast | xlvT | aggUT | wtrans x5 | cbprep ----------------
constexpr int PREP_LN = 4096;
constexpr int PREP_XLK = PREP_LN + 4096;       // 8192
constexpr int PREP_XLVT = PREP_XLK + 1024;     // 9216
constexpr int PREP_AGGUT = PREP_XLVT + 1024;   // 10240
constexpr int PREP_WT = PREP_AGGUT + 1280;     // 11520
constexpr int PREP_TOTAL = PREP_WT + 2048;     // 13568

__global__ __launch_bounds__(256) void prep_kernel(
    const float* __restrict__ x, const float* __restrict__ gw, const float* __restrict__ bw,
    ushort* __restrict__ xt_bf,
    const float* __restrict__ xlk, ushort* __restrict__ xlk_bf,
    const float* __restrict__ xlv, ushort* __restrict__ xlvT,
    const float* __restrict__ aggU, ushort* __restrict__ aggUT,
    const float* __restrict__ wq, const float* __restrict__ wk, const float* __restrict__ wv,
    const float* __restrict__ wg, const float* __restrict__ wres,
    ushort* __restrict__ wqkvg_t, ushort* __restrict__ wres_t,
    const float* __restrict__ cb, float* __restrict__ cbn, ushort* __restrict__ cb_bf) {
  __shared__ float tile[64][65];
  __shared__ float smc[4];
  const int bid = blockIdx.x;
  const int tid = threadIdx.x;

  if (bid < PREP_LN) {
    size_t row = bid;
    float4 v = ((const float4*)(x + row * nD))[tid];
    {
      int lane = tid & 63, w = tid >> 6;
      float s = v.x + v.y + v.z + v.w;
#pragma unroll
      for (int off = 32; off; off >>= 1) s += __shfl_down(s, off);
      if (lane == 0) smc[w] = s;
    }
    __syncthreads();
    float mu = (smc[0] + smc[1] + smc[2] + smc[3]) * (1.f / nD);
    __syncthreads();
    float4 d = make_float4(v.x - mu, v.y - mu, v.z - mu, v.w - mu);
    {
      int lane = tid & 63, w = tid >> 6;
      float s = d.x * d.x + d.y * d.y + d.z * d.z + d.w * d.w;
#pragma unroll
      for (int off = 32; off; off >>= 1) s += __shfl_down(s, off);
      if (lane == 0) smc[w] = s;
    }
    __syncthreads();
    float var = (smc[0] + smc[1] + smc[2] + smc[3]) * (1.f / nD);
    float rs = rsqrtf(var + 1e-6f);
    float4 gg = ((const float4*)gw)[tid];
    float4 bb = ((const float4*)bw)[tid];
    uint2 pb;
    pb.x = pk2(d.x * rs * gg.x + bb.x, d.y * rs * gg.y + bb.y);
    pb.y = pk2(d.z * rs * gg.z + bb.z, d.w * rs * gg.w + bb.w);
    ((uint2*)(xt_bf + row * nD))[tid] = pb;
  } else if (bid < PREP_XLK) {
    const int blk = bid - PREP_LN;
    size_t idx = (size_t)blk * 256 + tid;
    float4 v = ((const float4*)xlk)[idx];
    uint2 p;
    p.x = pk2(v.x, v.y);
    p.y = pk2(v.z, v.w);
    ((uint2*)xlk_bf)[idx] = p;
  } else if (bid < PREP_AGGUT) {
    // transpose-cast [bh][512][128] -> [bh][128][512]
    const bool isXlv = bid < PREP_XLVT;
    const int i = bid - (isXlv ? PREP_XLK : PREP_XLVT);
    const float* S = isXlv ? xlv : aggU;
    ushort* D = isXlv ? xlvT : aggUT;
    const int bh = i >> 4, t = i & 15;
    const int tok0 = (t >> 1) * 64, d0 = (t & 1) * 64;
    const float* src = S + ((size_t)bh * 512 + tok0) * 128 + d0;
    ushort* dst = D + ((size_t)bh * 128 + d0) * 512 + tok0;
    const int c = tid & 63, r4 = tid >> 6;
#pragma unroll
    for (int k = 0; k < 16; ++k) {
      int r = k * 4 + r4;
      tile[r][c] = src[(size_t)r * 128 + c];
    }
    __syncthreads();
#pragma unroll
    for (int k = 0; k < 16; ++k) {
      int dd = k * 4 + r4;
      dst[(size_t)dd * 512 + c] = f2bf(tile[c][dd]);
    }
  } else if (bid < PREP_WT) {
    const int i = bid - PREP_AGGUT;
    const int z = i >> 8, rem = i & 255;
    const int kz = (rem >> 4) * 64, nz = (rem & 15) * 64;
    const float* W;
    ushort* D;
    if (z == 0)      { W = wq;   D = wqkvg_t; }
    else if (z == 1) { W = wk;   D = wqkvg_t + (size_t)1024 * 1024; }
    else if (z == 2) { W = wv;   D = wqkvg_t + (size_t)2048 * 1024; }
    else if (z == 3) { W = wg;   D = wqkvg_t + (size_t)3072 * 1024; }
    else             { W = wres; D = wres_t; }
    const int c = tid & 63, r4 = tid >> 6;
#pragma unroll
    for (int k = 0; k < 16; ++k) {
      int r = k * 4 + r4;
      tile[r][c] = W[(size_t)(kz + r) * 1024 + nz + c];
    }
    __syncthreads();
#pragma unroll
    for (int k = 0; k < 16; ++k) {
      int n = k * 4 + r4;
      D[(size_t)(nz + n) * 1024 + kz + c] = f2bf(tile[c][n]);
    }
  } else {
    const int i = bid - PREP_WT;
    const int grp = tid >> 7, t128 = tid & 127;
    const int hc = i * 2 + grp;
    float v = cb[(size_t)hc * 128 + t128];
    cb_bf[(size_t)hc * 128 + t128] = f2bf(v);
    float s = v * v;
#pragma unroll
    for (int off = 32; off; off >>= 1) s += __shfl_down(s, off);
    if ((t128 & 63) == 0) smc[grp * 2 + (t128 >> 6)] = s;
    __syncthreads();
    if (t128 == 0) cbn[hc] = smc[grp * 2] + smc[grp * 2 + 1];
  }
}

// ---------------- v row-major bf16 -> vT[b][h][d][token] ----------------
__global__ __launch_bounds__(256) void vtrans_kernel(const ushort* __restrict__ vrow,
                                                     ushort* __restrict__ vT) {
  __shared__ ushort tile[64][72];
  const int i = blockIdx.x;
  const int bh = i >> 4, t = i & 15;
  const int b = bh >> 3, h = bh & 7;
  const int tok0 = (t >> 1) * 64, d0 = (t & 1) * 64;
  const int c = threadIdx.x & 63, r4 = threadIdx.x >> 6;
  const ushort* src = vrow + ((size_t)(b * nT + tok0)) * 1024 + h * 128 + d0;
#pragma unroll
  for (int k = 0; k < 16; ++k) {
    int r = k * 4 + r4;
    tile[r][c] = src[(size_t)r * 1024 + c];
  }
  __syncthreads();
  ushort* dst = vT + (((size_t)bh * 128 + d0) * 512 + tok0);
#pragma unroll
  for (int k = 0; k < 16; ++k) {
    int dd = k * 4 + r4;
    dst[(size_t)dd * 512 + c] = tile[c][dd];
  }
}

// ---------------- bf16 MFMA GEMM (128x128 tile, BK=32) ----------------
// MODE 0: fp32 -> C0.
// MODE 1: seg0 q -> hln+xu -> C1 bf16; seg1 k -> hln -> kbf bf16 + knorm2;
//         seg2 v -> C2 bf16 row-major; seg3 silu -> C3 bf16.
template <int MODE>
__global__ __launch_bounds__(256) void gemm_bf16_kernel(const ushort* __restrict__ A,
                                                        const ushort* __restrict__ Bt,
                                                        float* __restrict__ C0,
                                                        ushort* __restrict__ C1,
                                                        ushort* __restrict__ C2,
                                                        ushort* __restrict__ C3,
                                                        ushort* __restrict__ kbf,
                                                        float* __restrict__ knorm2,
                                                        const float* __restrict__ xu) {
  __shared__ __align__(16) ushort As[128 * 32];
  __shared__ __align__(16) ushort Bs[128 * 32];
  __shared__ float rowsum[128][2];
  __shared__ float rowsum2[128][2];
  const int tid = threadIdx.x;
  const int w = tid >> 6, l = tid & 63;
  const int lr = l & 15, lg = l >> 4;
  const int wr = w >> 1, wc = w & 1;
  const int n0 = blockIdx.x * 128;
  const int m0 = blockIdx.y * 128;
  constexpr int K = 1024;

  f32x4 acc[4][4];
#pragma unroll
  for (int i = 0; i < 4; ++i)
#pragma unroll
    for (int j = 0; j < 4; ++j) acc[i][j] = (f32x4){0.f, 0.f, 0.f, 0.f};

  const int e0 = w * 512 + l * 8;
  const int r0 = e0 >> 5, c0 = e0 & 31;
  const int e1 = 2048 + e0;
  const int r1 = e1 >> 5, c1 = e1 & 31;
  const ushort* a0p = A + (size_t)(m0 + r0) * K + c0;
  const ushort* a1p = A + (size_t)(m0 + r1) * K + c1;
  const ushort* b0p = Bt + (size_t)(n0 + r0) * K + c0;
  const ushort* b1p = Bt + (size_t)(n0 + r1) * K + c1;
  ushort* lA0 = &As[w * 512];
  ushort* lA1 = &As[2048 + w * 512];
  ushort* lB0 = &Bs[w * 512];
  ushort* lB1 = &Bs[2048 + w * 512];

  for (int k0 = 0; k0 < K; k0 += 32) {
    __syncthreads();
    gload16(a0p + k0, lA0);
    gload16(a1p + k0, lA1);
    gload16(b0p + k0, lB0);
    gload16(b1p + k0, lB1);
    __syncthreads();
    short8 af[4], bfr[4];
#pragma unroll
    for (int i = 0; i < 4; ++i) af[i] = *(const short8*)&As[(wr * 64 + i * 16 + lr) * 32 + lg * 8];
#pragma unroll
    for (int j = 0; j < 4; ++j) bfr[j] = *(const short8*)&Bs[(wc * 64 + j * 16 + lr) * 32 + lg * 8];
    __builtin_amdgcn_s_setprio(1);
#pragma unroll
    for (int i = 0; i < 4; ++i)
#pragma unroll
      for (int j = 0; j < 4; ++j)
        acc[i][j] = __builtin_amdgcn_mfma_f32_16x16x32_bf16(af[i], bfr[j], acc[i][j], 0, 0, 0);
    __builtin_amdgcn_s_setprio(0);
  }

  const int seg = n0 >> 10;
  const int nbase = n0 & 1023;
  if (MODE == 1 && seg <= 1) {
    const int h = nbase >> 7;
    float ps[4][4], ps2[4][4];
#pragma unroll
    for (int i = 0; i < 4; ++i)
#pragma unroll
      for (int r2 = 0; r2 < 4; ++r2) {
        float s = 0.f, s2 = 0.f;
#pragma unroll
        for (int j = 0; j < 4; ++j) {
          float v = acc[i][j][r2];
          s += v;
          s2 += v * v;
        }
#pragma unroll
        for (int off = 1; off < 16; off <<= 1) {
          s += __shfl_xor(s, off);
          s2 += __shfl_xor(s2, off);
        }
        ps[i][r2] = s;
        ps2[i][r2] = s2;
      }
    if (lr == 0) {
#pragma unroll
      for (int i = 0; i < 4; ++i)
#pragma unroll
        for (int r2 = 0; r2 < 4; ++r2) {
          int rloc = wr * 64 + i * 16 + lg * 4 + r2;
          rowsum[rloc][wc] = ps[i][r2];
          rowsum2[rloc][wc] = ps2[i][r2];
        }
    }
    __syncthreads();
#pragma unroll
    for (int i = 0; i < 4; ++i)
#pragma unroll
      for (int r2 = 0; r2 < 4; ++r2) {
        const int rloc = wr * 64 + i * 16 + lg * 4 + r2;
        const int grow = m0 + rloc;
        float tot = rowsum[rloc][0] + rowsum[rloc][1];
        float tot2 = rowsum2[rloc][0] + rowsum2[rloc][1];
        float mu = tot * (1.f / 128.f);
        float qf = tot2 - 128.f * mu * mu;
        float rs = rsqrtf(qf * (1.f / 128.f) + 1e-6f);
#pragma unroll
        for (int j = 0; j < 4; ++j) {
          const int col = wc * 64 + j * 16 + lr;
          float v = (acc[i][j][r2] - mu) * rs;
          if (seg == 0) {
            v += xu[h * 128 + col];
            C1[(size_t)grow * 1024 + nbase + col] = f2bf(v);
          } else {
            kbf[(size_t)grow * 1024 + nbase + col] = f2bf(v);
          }
        }
        if (seg == 1 && lr == 0 && wc == 0) knorm2[(size_t)grow * 8 + h] = qf * rs * rs;
      }
  } else {
#pragma unroll
    for (int i = 0; i < 4; ++i)
#pragma unroll
      for (int j = 0; j < 4; ++j)
#pragma unroll
        for (int r2 = 0; r2 < 4; ++r2) {
          const int row = m0 + wr * 64 + i * 16 + lg * 4 + r2;
          const int col = wc * 64 + j * 16 + lr;
          float v = acc[i][j][r2];
          if (MODE == 0) {
            C0[(size_t)row * 1024 + n0 + col] = v;
          } else {
            const int nloc = nbase + col;
            if (seg == 2) {
              C2[(size_t)row * 1024 + nloc] = f2bf(v);
            } else {
              float s = v / (1.f + __expf(-v));
              C3[(size_t)row * 1024 + nloc] = f2bf(s);
            }
          }
        }
  }
}

// ---------------- MFMA VQ: argmin over 512 codes via k.c MFMA ----------------
__global__ __launch_bounds__(256) void vq_mfma_kernel(const ushort* __restrict__ kbf,
                                                      const ushort* __restrict__ cb_bf,
                                                      const float* __restrict__ cbn,
                                                      const float* __restrict__ knorm2,
                                                      const float* __restrict__ mask,
                                                      ushort* __restrict__ khat_bf,
                                                      float* __restrict__ blocksq) {
  __shared__ ushort Kb[64][136];
  __shared__ ushort Cb[64][136];
  __shared__ float cnsh[64];
  __shared__ int zsh[64];
  __shared__ float dsh[64];
  const int tid = threadIdx.x;
  const int w = tid >> 6, l = tid & 63;
  const int lr = l & 15, lg = l >> 4;
  const int b = blockIdx.y >> 3, h = blockIdx.y & 7;
  const int t0 = blockIdx.x * 64;
  const int srow = tid >> 2, sd = (tid & 3) * 32;

  {
    const ushort* src = kbf + ((size_t)((b * nT + t0 + srow) * nH + h)) * 128 + sd;
    *(uint4*)&Kb[srow][sd] = *(const uint4*)src;
    *(uint4*)&Kb[srow][sd + 8] = *(const uint4*)(src + 8);
    *(uint4*)&Kb[srow][sd + 16] = *(const uint4*)(src + 16);
    *(uint4*)&Kb[srow][sd + 24] = *(const uint4*)(src + 24);
  }
  __syncthreads();

  short8 af[4];
#pragma unroll
  for (int k0 = 0; k0 < 4; ++k0) af[k0] = *(const short8*)&Kb[w * 16 + lr][k0 * 32 + lg * 8];

  float best[4] = {1e30f, 1e30f, 1e30f, 1e30f};
  int bidx[4] = {0, 0, 0, 0};

  for (int cc = 0; cc < 8; ++cc) {
    __syncthreads();
    {
      const ushort* src = cb_bf + ((size_t)(h * nC + cc * 64 + srow)) * 128 + sd;
      *(uint4*)&Cb[srow][sd] = *(const uint4*)src;
      *(uint4*)&Cb[srow][sd + 8] = *(const uint4*)(src + 8);
      *(uint4*)&Cb[srow][sd + 16] = *(const uint4*)(src + 16);
      *(uint4*)&Cb[srow][sd + 24] = *(const uint4*)(src + 24);
      if (tid < 64) cnsh[tid] = cbn[h * nC + cc * 64 + tid];
    }
    __syncthreads();
#pragma unroll
    for (int ct = 0; ct < 4; ++ct) {
      f32x4 z = (f32x4){0.f, 0.f, 0.f, 0.f};
#pragma unroll
      for (int k0 = 0; k0 < 4; ++k0) {
        short8 cf = *(const short8*)&Cb[ct * 16 + lr][k0 * 32 + lg * 8];
        z = __builtin_amdgcn_mfma_f32_16x16x32_bf16(af[k0], cf, z, 0, 0, 0);
      }
      const int code = cc * 64 + ct * 16 + lr;
      const float cn = cnsh[ct * 16 + lr];
#pragma unroll
      for (int r2 = 0; r2 < 4; ++r2) {
        float d = cn - 2.f * z[r2];
        if (d < best[r2]) { best[r2] = d; bidx[r2] = code; }
      }
    }
  }

#pragma unroll
  for (int off = 1; off < 16; off <<= 1) {
#pragma unroll
    for (int r2 = 0; r2 < 4; ++r2) {
      float od = __shfl_xor(best[r2], off);
      int oi = __shfl_xor(bidx[r2], off);
      if (od < best[r2] || (od == best[r2] && oi < bidx[r2])) { best[r2] = od; bidx[r2] = oi; }
    }
  }
  if (lr == 0) {
#pragma unroll
    for (int r2 = 0; r2 < 4; ++r2) {
      int row = w * 16 + lg * 4 + r2;
      zsh[row] = bidx[r2];
      dsh[row] = best[r2];
    }
  }
  __syncthreads();

  {
    const int row = tid >> 2, part = (tid & 3) * 32;
    const ushort* src = cb_bf + ((size_t)(h * nC + zsh[row])) * 128 + part;
    ushort* dst = khat_bf + ((size_t)((b * nT + t0 + row) * nH + h)) * 128 + part;
    *(uint4*)dst = *(const uint4*)src;
    *(uint4*)(dst + 8) = *(const uint4*)(src + 8);
    *(uint4*)(dst + 16) = *(const uint4*)(src + 16);
    *(uint4*)(dst + 24) = *(const uint4*)(src + 24);
  }

  if (tid < 64) {
    float s = mask[b * nT + t0 + tid] *
              (knorm2[(size_t)(b * nT + t0 + tid) * nH + h] + dsh[tid]);
#pragma unroll
    for (int off = 32; off; off >>= 1) s += __shfl_down(s, off);
    if (tid == 0) blocksq[blockIdx.y * gridDim.x + blockIdx.x] = s;
  }
}

// ---------------- MFMA flash attention: async 2-phase via gload_lds ping-pong ----------------
// grid = (bh, t0/64): linear id % 8 = h -> same-(b,h) blocks on one XCD (L2 share).
// K staged row-major [64][128], V staged d-major [128][64] (from pre-transposed vT globals),
// both with XOR swizzle byte^=((row&7)<<4) applied at SOURCE (gload is linear-dest) and READ.
__global__ __launch_bounds__(256) void attn_mfma_kernel(
    const ushort* __restrict__ qb, const ushort* __restrict__ khat,
    const ushort* __restrict__ vbufT, const ushort* __restrict__ xlk,
    const ushort* __restrict__ xlvT, const ushort* __restrict__ cbb,
    const ushort* __restrict__ aggUT, const float* __restrict__ aggL,
    const ushort* __restrict__ gbuf, ushort* __restrict__ o) {
  __shared__ __align__(16) ushort Ks[2][64][128];
  __shared__ __align__(16) ushort Vts[2][128][64];
  __shared__ ushort Ps[4][16][72];
  __shared__ float lowb[2][64];

  const int tid = threadIdx.x;
  const int w = tid >> 6, l = tid & 63;
  const int lr = l & 15, lg = l >> 4;
  const int b = blockIdx.x >> 3, h = blockIdx.x & 7;
  const int t0 = blockIdx.y * 64;

  short8 qf[4];
  {
    const ushort* qrow = qb + ((size_t)((b * nT + t0 + w * 16 + lr) * nH + h)) * 128;
#pragma unroll
    for (int k0 = 0; k0 < 4; ++k0) qf[k0] = *(const short8*)(qrow + k0 * 32 + lg * 8);
  }

  float m_r[4] = {-1e30f, -1e30f, -1e30f, -1e30f};
  float l_r[4] = {0.f, 0.f, 0.f, 0.f};
  f32x4 acc_o[8];
#pragma unroll
  for (int dt = 0; dt < 8; ++dt) acc_o[dt] = (f32x4){0.f, 0.f, 0.f, 0.f};

  const int nch = t0 / 64 + 9;
  const int ntot = nch + 8;

  auto stage = [&](int ci) {
    const int buf = ci & 1;
    const bool isAgg = ci >= nch;
    const int sb = isAgg ? (ci - nch) * 64 : ci * 64;
    char* kdst = (char*)&Ks[buf][0][0];
    char* vdst = (char*)&Vts[buf][0][0];
#pragma unroll
    for (int j = 0; j < 4; ++j) {
      {
        const int row = w * 16 + j * 4 + (l >> 4);
        const int scol = ((l & 15) * 16) ^ ((row & 7) << 4);
        const ushort* srow;
        if (isAgg) {
          srow = cbb + ((size_t)(h * nC + sb + row)) * 128;
        } else {
          const int s = sb + row;
          srow = (s < nM) ? xlk + ((size_t)(b * nH + h) * nM + s) * 128
                          : khat + ((size_t)((b * nT + (s - nM)) * nH + h)) * 128;
        }
        gload16((const char*)srow + scol, kdst + w * 4096 + j * 1024);
      }
      {
        const int d = w * 32 + j * 8 + (l >> 3);
        const int skb = ((l & 7) * 16) ^ ((d & 7) << 4);
        const ushort* srow;
        if (isAgg) {
          srow = aggUT + (((size_t)(b * nH + h) * 128 + d) * 512 + sb);
        } else if (sb < nM) {
          srow = xlvT + (((size_t)(b * nH + h) * 128 + d) * 512 + sb);
        } else {
          srow = vbufT + (((size_t)(b * nH + h) * 128 + d) * 512 + (sb - nM));
        }
        gload16((const char*)srow + skb, vdst + w * 4096 + j * 1024);
      }
    }
    if (isAgg && w == 0) {
      gload4(aggL + (size_t)(b * nH + h) * nC + sb + l, &lowb[buf][0]);
    }
  };

  auto chunk_body = [&](int ci) {
    const int buf = ci & 1;
    const bool AGG = ci >= nch;
    const bool MASKQ = ci == nch - 1;
    const int sbase = AGG ? 0 : ci * 64;   // sbase only used for mask (recent)
    const char* ksb = (const char*)&Ks[buf][0][0];
    const char* vsb = (const char*)&Vts[buf][0][0];
    f32x4 sc[4];
    __builtin_amdgcn_s_setprio(1);
#pragma unroll
    for (int kt = 0; kt < 4; ++kt) {
      f32x4 z = (f32x4){0.f, 0.f, 0.f, 0.f};
      const int R = kt * 16 + lr;
#pragma unroll
      for (int k0 = 0; k0 < 4; ++k0) {
        short8 kf = *(const short8*)(ksb + R * 256 + ((k0 * 64 + lg * 16) ^ ((R & 7) << 4)));
        z = __builtin_amdgcn_mfma_f32_16x16x32_bf16(qf[k0], kf, z, 0, 0, 0);
      }
      sc[kt] = z;
    }
    __builtin_amdgcn_s_setprio(0);
    float sv[4][4];
    float pm[4] = {-1e30f, -1e30f, -1e30f, -1e30f};
#pragma unroll
    for (int kt = 0; kt < 4; ++kt)
#pragma unroll
      for (int r2 = 0; r2 < 4; ++r2) {
        float s = sc[kt][r2] * RTAU;
        if (MASKQ) {
          int key = sbase + kt * 16 + lr;
          int tl = t0 + w * 16 + lg * 4 + r2 + nM;
          if (key > tl) s = -1e30f;
        }
        sv[kt][r2] = s;
        pm[r2] = fmaxf(pm[r2], s);
      }
#pragma unroll
    for (int r2 = 0; r2 < 4; ++r2)
#pragma unroll
      for (int off = 1; off < 16; off <<= 1) pm[r2] = fmaxf(pm[r2], __shfl_xor(pm[r2], off));
    float scale[4], rs[4];
#pragma unroll
    for (int r2 = 0; r2 < 4; ++r2) {
      float mn = fmaxf(m_r[r2], pm[r2]);
      scale[r2] = __expf(m_r[r2] - mn);
      m_r[r2] = mn;
      rs[r2] = 0.f;
    }
#pragma unroll
    for (int kt = 0; kt < 4; ++kt)
#pragma unroll
      for (int r2 = 0; r2 < 4; ++r2) {
        float p = __expf(sv[kt][r2] - m_r[r2]);
        rs[r2] += AGG ? p * lowb[buf][kt * 16 + lr] : p;
        Ps[w][lg * 4 + r2][kt * 16 + lr] = f2bf(p);
      }
#pragma unroll
    for (int r2 = 0; r2 < 4; ++r2)
#pragma unroll
      for (int off = 1; off < 16; off <<= 1) rs[r2] += __shfl_xor(rs[r2], off);
#pragma unroll
    for (int r2 = 0; r2 < 4; ++r2) l_r[r2] = l_r[r2] * scale[r2] + rs[r2];
#pragma unroll
    for (int dt = 0; dt < 8; ++dt)
#pragma unroll
      for (int r2 = 0; r2 < 4; ++r2) acc_o[dt][r2] *= scale[r2];
    short8 pa0 = *(const short8*)&Ps[w][lr][lg * 8];
    short8 pa1 = *(const short8*)&Ps[w][lr][32 + lg * 8];
    __builtin_amdgcn_s_setprio(1);
#pragma unroll
    for (int dt = 0; dt < 8; ++dt) {
      const int R2 = dt * 16 + lr;
      short8 vf0 = *(const short8*)(vsb + R2 * 128 + ((lg * 16) ^ ((R2 & 7) << 4)));
      short8 vf1 = *(const short8*)(vsb + R2 * 128 + ((64 + lg * 16) ^ ((R2 & 7) << 4)));
      acc_o[dt] = __builtin_amdgcn_mfma_f32_16x16x32_bf16(pa0, vf0, acc_o[dt], 0, 0, 0);
      acc_o[dt] = __builtin_amdgcn_mfma_f32_16x16x32_bf16(pa1, vf1, acc_o[dt], 0, 0, 0);
    }
    __builtin_amdgcn_s_setprio(0);
  };

  stage(0);
  __syncthreads();
  for (int ci = 0; ci < ntot; ++ci) {
    if (ci + 1 < ntot) stage(ci + 1);   // async into the other buffer
    chunk_body(ci);
    __syncthreads();                    // drains prefetch (had full compute to land)
  }

  float inv[4];
#pragma unroll
  for (int r2 = 0; r2 < 4; ++r2) inv[r2] = 1.f / l_r[r2];
#pragma unroll
  for (int dt = 0; dt < 8; ++dt)
#pragma unroll
    for (int r2 = 0; r2 < 4; ++r2) {
      int trow = t0 + w * 16 + lg * 4 + r2;
      size_t oi = ((size_t)(b * nT + trow)) * nD + h * 128 + dt * 16 + lr;
      float gv = bf2f(gbuf[oi]);
      o[oi] = f2bf(acc_o[dt][r2] * inv[r2] * gv);
    }
}

// ---------------- losses ----------------
__global__ __launch_bounds__(256) void finalize_kernel(const float* __restrict__ blocksq,
                                                       int nblk,
                                                       const float* __restrict__ mask,
                                                       float* __restrict__ outp) {
  __shared__ float sm[8];
  const int tid = threadIdx.x;
  float s = 0.f, ms = 0.f;
  for (int i = tid; i < NROW; i += 256) {
    if (i < nblk) s += blocksq[i];
    ms += mask[i];
  }
#pragma unroll
  for (int off = 32; off; off >>= 1) { s += __shfl_down(s, off); ms += __shfl_down(ms, off); }
  if ((tid & 63) == 0) { sm[tid >> 6] = s; sm[4 + (tid >> 6)] = ms; }
  __syncthreads();
  if (tid == 0) {
    float ts = sm[0] + sm[1] + sm[2] + sm[3];
    float tm = sm[4] + sm[5] + sm[6] + sm[7];
    float l = ts / (tm * (float)nH + 1e-6f);
    outp[0] = l;
    outp[1] = l;
  }
}

}  // namespace

extern "C" void kernel_launch(void* const* d_in, const int* in_sizes, int n_in,
                              void* d_out, int out_size, void* d_ws, size_t ws_size,
                              hipStream_t stream) {
  const float* x    = (const float*)d_in[0];
  const float* mask = (const float*)d_in[2];
  const float* xlk  = (const float*)d_in[3];
  const float* xlv  = (const float*)d_in[4];
  const float* aggU = (const float*)d_in[5];
  const float* aggL = (const float*)d_in[6];
  const float* wlng = (const float*)d_in[7];
  const float* wlnb = (const float*)d_in[8];
  const float* wq   = (const float*)d_in[9];
  const float* wk   = (const float*)d_in[10];
  const float* wv   = (const float*)d_in[11];
  const float* wg   = (const float*)d_in[12];
  const float* wres = (const float*)d_in[13];
  const float* xu   = (const float*)d_in[14];
  const float* cb   = (const float*)d_in[15];
  float* out = (float*)d_out;

  float* ws = (float*)d_ws;
  const size_t SZ = (size_t)NROW * nD;   // 4,194,304
  float*  kregion = ws;                                    // SZ floats: kbf (first half) + vrow (second half)
  ushort* qbuf_bf = (ushort*)(ws + SZ);                    // SZ ushorts
  ushort* khat_bf = (ushort*)(ws + SZ + SZ / 2);           // SZ ushorts
  ushort* vbufT   = (ushort*)(ws + 2 * SZ);                // SZ ushorts [b][h][d][tok]
  ushort* gbuf_bf = (ushort*)(ws + 2 * SZ + SZ / 2);       // SZ ushorts
  ushort* xt_bf   = (ushort*)(ws + 3 * SZ);                // SZ ushorts (obuf overlay)
  ushort* wqkvg_t = (ushort*)(ws + 3 * SZ + SZ / 2);       // SZ ushorts
  ushort* wres_t  = (ushort*)(ws + 4 * SZ);                // 1M ushorts
  ushort* xlk_bf  = (ushort*)(ws + 4 * SZ + SZ / 8);       // SZ ushorts
  ushort* xlvT    = (ushort*)(ws + 4 * SZ + SZ / 8 + SZ / 2);   // SZ ushorts
  ushort* aggUT   = (ushort*)(ws + 4 * SZ + SZ / 8 + SZ);       // SZ ushorts
  ushort* cb_bf   = (ushort*)(ws + 4 * SZ + SZ / 8 + 3 * SZ / 2);
  float*  cbn     = ws + 4 * SZ + SZ / 8 + 3 * SZ / 2 + SZ / 16;
  float*  knorm2  = cbn + 4096;
  float*  bsq     = knorm2 + 32768;
  ushort* kbf     = (ushort*)kregion;            // SZ ushorts
  ushort* vrow    = (ushort*)(ws + SZ / 2);      // SZ ushorts (second half of kregion)
  ushort* obuf_bf = xt_bf;

  prep_kernel<<<PREP_TOTAL, 256, 0, stream>>>(
      x, wlng, wlnb, xt_bf, xlk, xlk_bf, xlv, xlvT, aggU, aggUT,
      wq, wk, wv, wg, wres, wqkvg_t, wres_t, cb, cbn, cb_bf);

  gemm_bf16_kernel<1><<<dim3(32, 32), 256, 0, stream>>>(
      xt_bf, wqkvg_t, nullptr, qbuf_bf, vrow, gbuf_bf, kbf, knorm2, xu);

  vtrans_kernel<<<1024, 256, 0, stream>>>(vrow, vbufT);

  vq_mfma_kernel<<<dim3(nT / 64, nB * nH), 256, 0, stream>>>(kbf, cb_bf, cbn, knorm2,
                                                             mask, khat_bf, bsq);

  attn_mfma_kernel<<<dim3(nB * nH, nT / 64), 256, 0, stream>>>(
      qbuf_bf, khat_bf, vbufT, xlk_bf, xlvT, cb_bf, aggUT, aggL, gbuf_bf, obuf_bf);

  gemm_bf16_kernel<0><<<dim3(8, 32), 256, 0, stream>>>(
      obuf_bf, wres_t, out, nullptr, nullptr, nullptr, nullptr, nullptr, nullptr);
  finalize_kernel<<<1, 256, 0, stream>>>(bsq, nT / 64 * nB * nH, mask, out + SZ);
}

// Round 23
// 219.352 us; speedup vs baseline: 1.2560x; 1.0693x over previous
//
#include <hip/hip_runtime.h>
#include <math.h>

namespace {

constexpr int nB = 8, nT = 512, nD = 1024, nH = 8, nDK = 128, nDV = 128, nC = 512, nM = 512;
constexpr int NROW = nB * nT;                  // 4096
constexpr float RTAU = 0.08838834764831845f;   // 1/sqrt(128)

typedef __attribute__((ext_vector_type(8))) short short8;
typedef __attribute__((ext_vector_type(4))) float f32x4;

__device__ __forceinline__ ushort f2bf(float f) {
  union { float f; uint u; } x; x.f = f;
  uint r = x.u + 0x7fff + ((x.u >> 16) & 1);
  return (ushort)(r >> 16);
}
__device__ __forceinline__ uint pk2(float a, float b) {
  return (uint)f2bf(a) | ((uint)f2bf(b) << 16);
}
__device__ __forceinline__ float bf2f(ushort u) {
  return __uint_as_float(((uint)u) << 16);
}
__device__ __forceinline__ void gload16(const void* g, void* l) {
  __builtin_amdgcn_global_load_lds((const __attribute__((address_space(1))) void*)g,
                                   (__attribute__((address_space(3))) void*)l, 16, 0, 0);
}

// ---------------- fused prep: ln | tobf x3 | wtrans x5 | cbprep ----------------
constexpr int PREP_LN = 4096;
constexpr int PREP_CAST = PREP_LN + 12288;   // 16384
constexpr int PREP_WT = PREP_CAST + 1280;    // 17664
constexpr int PREP_CB = PREP_WT + 2048;      // 19712

__global__ __launch_bounds__(256) void prep_kernel(
    const float* __restrict__ x, const float* __restrict__ gw, const float* __restrict__ bw,
    ushort* __restrict__ xt_bf,
    const float* __restrict__ xlk, ushort* __restrict__ xlk_bf,
    const float* __restrict__ xlv, ushort* __restrict__ xlv_bf,
    const float* __restrict__ aggU, ushort* __restrict__ aggU_bf,
    const float* __restrict__ wq, const float* __restrict__ wk, const float* __restrict__ wv,
    const float* __restrict__ wg, const float* __restrict__ wres,
    ushort* __restrict__ wqkvg_t, ushort* __restrict__ wres_t,
    const float* __restrict__ cb, float* __restrict__ cbn, ushort* __restrict__ cb_bf) {
  __shared__ float tile[64][65];
  __shared__ float smc[4];
  const int bid = blockIdx.x;
  const int tid = threadIdx.x;

  if (bid < PREP_LN) {
    size_t row = bid;
    float4 v = ((const float4*)(x + row * nD))[tid];
    {
      int lane = tid & 63, w = tid >> 6;
      float s = v.x + v.y + v.z + v.w;
#pragma unroll
      for (int off = 32; off; off >>= 1) s += __shfl_down(s, off);
      if (lane == 0) smc[w] = s;
    }
    __syncthreads();
    float mu = (smc[0] + smc[1] + smc[2] + smc[3]) * (1.f / nD);
    __syncthreads();
    float4 d = make_float4(v.x - mu, v.y - mu, v.z - mu, v.w - mu);
    {
      int lane = tid & 63, w = tid >> 6;
      float s = d.x * d.x + d.y * d.y + d.z * d.z + d.w * d.w;
#pragma unroll
      for (int off = 32; off; off >>= 1) s += __shfl_down(s, off);
      if (lane == 0) smc[w] = s;
    }
    __syncthreads();
    float var = (smc[0] + smc[1] + smc[2] + smc[3]) * (1.f / nD);
    float rs = rsqrtf(var + 1e-6f);
    float4 gg = ((const float4*)gw)[tid];
    float4 bb = ((const float4*)bw)[tid];
    uint2 pb;
    pb.x = pk2(d.x * rs * gg.x + bb.x, d.y * rs * gg.y + bb.y);
    pb.y = pk2(d.z * rs * gg.z + bb.z, d.w * rs * gg.w + bb.w);
    ((uint2*)(xt_bf + row * nD))[tid] = pb;
  } else if (bid < PREP_CAST) {
    const int i = bid - PREP_LN;
    const int which = i >> 12, blk = i & 4095;
    const float* src = which == 0 ? xlk : (which == 1 ? xlv : aggU);
    ushort* dst = which == 0 ? xlk_bf : (which == 1 ? xlv_bf : aggU_bf);
    size_t idx = (size_t)blk * 256 + tid;
    float4 v = ((const float4*)src)[idx];
    uint2 p;
    p.x = pk2(v.x, v.y);
    p.y = pk2(v.z, v.w);
    ((uint2*)dst)[idx] = p;
  } else if (bid < PREP_WT) {
    const int i = bid - PREP_CAST;
    const int z = i >> 8, rem = i & 255;
    const int kz = (rem >> 4) * 64, nz = (rem & 15) * 64;
    const float* W;
    ushort* D;
    if (z == 0)      { W = wq;   D = wqkvg_t; }
    else if (z == 1) { W = wk;   D = wqkvg_t + (size_t)1024 * 1024; }
    else if (z == 2) { W = wv;   D = wqkvg_t + (size_t)2048 * 1024; }
    else if (z == 3) { W = wg;   D = wqkvg_t + (size_t)3072 * 1024; }
    else             { W = wres; D = wres_t; }
    const int c = tid & 63, r4 = tid >> 6;
#pragma unroll
    for (int k = 0; k < 16; ++k) {
      int r = k * 4 + r4;
      tile[r][c] = W[(size_t)(kz + r) * 1024 + nz + c];
    }
    __syncthreads();
#pragma unroll
    for (int k = 0; k < 16; ++k) {
      int n = k * 4 + r4;
      D[(size_t)(nz + n) * 1024 + kz + c] = f2bf(tile[c][n]);
    }
  } else {
    const int i = bid - PREP_WT;
    const int grp = tid >> 7, t128 = tid & 127;
    const int hc = i * 2 + grp;
    float v = cb[(size_t)hc * 128 + t128];
    cb_bf[(size_t)hc * 128 + t128] = f2bf(v);
    float s = v * v;
#pragma unroll
    for (int off = 32; off; off >>= 1) s += __shfl_down(s, off);
    if ((t128 & 63) == 0) smc[grp * 2 + (t128 >> 6)] = s;
    __syncthreads();
    if (t128 == 0) cbn[hc] = smc[grp * 2] + smc[grp * 2 + 1];
  }
}

// ---------------- bf16 MFMA GEMM (128x128 tile, BK=64, XOR-swizzled LDS) ----------------
// Swizzle (rule 21): linear LDS dest for gload_lds; SOURCE byte offset ^ ((row&7)<<4);
// same XOR on LDS reads. Kills the 8-way bank conflict of the row-major [128][BK] tile.
// MODE 0: fp32 -> C0.
// MODE 1: seg0 q -> hln+xu -> C1 bf16; seg1 k -> hln -> kbf bf16 + knorm2;
//         seg2 v -> C2 bf16; seg3 silu -> C3 bf16.
template <int MODE>
__global__ __launch_bounds__(256) void gemm_bf16_kernel(const ushort* __restrict__ A,
                                                        const ushort* __restrict__ Bt,
                                                        float* __restrict__ C0,
                                                        ushort* __restrict__ C1,
                                                        ushort* __restrict__ C2,
                                                        ushort* __restrict__ C3,
                                                        ushort* __restrict__ kbf,
                                                        float* __restrict__ knorm2,
                                                        const float* __restrict__ xu) {
  __shared__ __align__(16) ushort As[128 * 64];
  __shared__ __align__(16) ushort Bs[128 * 64];
  __shared__ float rowsum[128][2];
  __shared__ float rowsum2[128][2];
  const int tid = threadIdx.x;
  const int w = tid >> 6, l = tid & 63;
  const int lr = l & 15, lg = l >> 4;
  const int wr = w >> 1, wc = w & 1;
  const int n0 = blockIdx.x * 128;
  const int m0 = blockIdx.y * 128;
  constexpr int K = 1024;

  f32x4 acc[4][4];
#pragma unroll
  for (int i = 0; i < 4; ++i)
#pragma unroll
    for (int j = 0; j < 4; ++j) acc[i][j] = (f32x4){0.f, 0.f, 0.f, 0.f};

  // staging: [128][64] tile, 4 rounds x 256 thr x 8 elems (16B)
  const int eb = w * 512 + l * 8;
  int rowA[4], sof[4], eo[4];
#pragma unroll
  for (int r = 0; r < 4; ++r) {
    int e = r * 2048 + eb;
    rowA[r] = e >> 6;
    eo[r] = e * 2;                               // linear LDS byte offset
    sof[r] = ((e & 63) * 2) ^ ((rowA[r] & 7) << 4);  // swizzled source byte offset
  }

  for (int k0 = 0; k0 < K; k0 += 64) {
    __syncthreads();
#pragma unroll
    for (int r = 0; r < 4; ++r) {
      gload16((const char*)(A + (size_t)(m0 + rowA[r]) * K + k0) + sof[r], (char*)As + eo[r]);
      gload16((const char*)(Bt + (size_t)(n0 + rowA[r]) * K + k0) + sof[r], (char*)Bs + eo[r]);
    }
    __syncthreads();
#pragma unroll
    for (int kk = 0; kk < 2; ++kk) {
      short8 af[4], bfr[4];
#pragma unroll
      for (int i = 0; i < 4; ++i) {
        const int row = wr * 64 + i * 16 + lr;
        af[i] = *(const short8*)((const char*)As + row * 128 +
                                 ((kk * 64 + lg * 16) ^ ((row & 7) << 4)));
      }
#pragma unroll
      for (int j = 0; j < 4; ++j) {
        const int row = wc * 64 + j * 16 + lr;
        bfr[j] = *(const short8*)((const char*)Bs + row * 128 +
                                  ((kk * 64 + lg * 16) ^ ((row & 7) << 4)));
      }
      __builtin_amdgcn_s_setprio(1);
#pragma unroll
      for (int i = 0; i < 4; ++i)
#pragma unroll
        for (int j = 0; j < 4; ++j)
          acc[i][j] = __builtin_amdgcn_mfma_f32_16x16x32_bf16(af[i], bfr[j], acc[i][j], 0, 0, 0);
      __builtin_amdgcn_s_setprio(0);
    }
  }

  const int seg = n0 >> 10;
  const int nbase = n0 & 1023;
  if (MODE == 1 && seg <= 1) {
    const int h = nbase >> 7;
    float ps[4][4], ps2[4][4];
#pragma unroll
    for (int i = 0; i < 4; ++i)
#pragma unroll
      for (int r2 = 0; r2 < 4; ++r2) {
        float s = 0.f, s2 = 0.f;
#pragma unroll
        for (int j = 0; j < 4; ++j) {
          float v = acc[i][j][r2];
          s += v;
          s2 += v * v;
        }
#pragma unroll
        for (int off = 1; off < 16; off <<= 1) {
          s += __shfl_xor(s, off);
          s2 += __shfl_xor(s2, off);
        }
        ps[i][r2] = s;
        ps2[i][r2] = s2;
      }
    if (lr == 0) {
#pragma unroll
      for (int i = 0; i < 4; ++i)
#pragma unroll
        for (int r2 = 0; r2 < 4; ++r2) {
          int rloc = wr * 64 + i * 16 + lg * 4 + r2;
          rowsum[rloc][wc] = ps[i][r2];
          rowsum2[rloc][wc] = ps2[i][r2];
        }
    }
    __syncthreads();
#pragma unroll
    for (int i = 0; i < 4; ++i)
#pragma unroll
      for (int r2 = 0; r2 < 4; ++r2) {
        const int rloc = wr * 64 + i * 16 + lg * 4 + r2;
        const int grow = m0 + rloc;
        float tot = rowsum[rloc][0] + rowsum[rloc][1];
        float tot2 = rowsum2[rloc][0] + rowsum2[rloc][1];
        float mu = tot * (1.f / 128.f);
        float qf = tot2 - 128.f * mu * mu;
        float rs = rsqrtf(qf * (1.f / 128.f) + 1e-6f);
#pragma unroll
        for (int j = 0; j < 4; ++j) {
          const int col = wc * 64 + j * 16 + lr;
          float v = (acc[i][j][r2] - mu) * rs;
          if (seg == 0) {
            v += xu[h * 128 + col];
            C1[(size_t)grow * 1024 + nbase + col] = f2bf(v);
          } else {
            kbf[(size_t)grow * 1024 + nbase + col] = f2bf(v);
          }
        }
        if (seg == 1 && lr == 0 && wc == 0) knorm2[(size_t)grow * 8 + h] = qf * rs * rs;
      }
  } else {
#pragma unroll
    for (int i = 0; i < 4; ++i)
#pragma unroll
      for (int j = 0; j < 4; ++j)
#pragma unroll
        for (int r2 = 0; r2 < 4; ++r2) {
          const int row = m0 + wr * 64 + i * 16 + lg * 4 + r2;
          const int col = wc * 64 + j * 16 + lr;
          float v = acc[i][j][r2];
          if (MODE == 0) {
            C0[(size_t)row * 1024 + n0 + col] = v;
          } else {
            const int nloc = nbase + col;
            if (seg == 2) {
              C2[(size_t)row * 1024 + nloc] = f2bf(v);
            } else {
              float s = v / (1.f + __expf(-v));
              C3[(size_t)row * 1024 + nloc] = f2bf(s);
            }
          }
        }
  }
}

// ---------------- MFMA VQ: argmin over 512 codes via k.c MFMA ----------------
__global__ __launch_bounds__(256) void vq_mfma_kernel(const ushort* __restrict__ kbf,
                                                      const ushort* __restrict__ cb_bf,
                                                      const float* __restrict__ cbn,
                                                      const float* __restrict__ knorm2,
                                                      const float* __restrict__ mask,
                                                      ushort* __restrict__ khat_bf,
                                                      float* __restrict__ blocksq) {
  __shared__ ushort Kb[64][136];
  __shared__ ushort Cb[64][136];
  __shared__ float cnsh[64];
  __shared__ int zsh[64];
  __shared__ float dsh[64];
  const int tid = threadIdx.x;
  const int w = tid >> 6, l = tid & 63;
  const int lr = l & 15, lg = l >> 4;
  const int b = blockIdx.y >> 3, h = blockIdx.y & 7;
  const int t0 = blockIdx.x * 64;
  const int srow = tid >> 2, sd = (tid & 3) * 32;

  {
    const ushort* src = kbf + ((size_t)((b * nT + t0 + srow) * nH + h)) * 128 + sd;
    *(uint4*)&Kb[srow][sd] = *(const uint4*)src;
    *(uint4*)&Kb[srow][sd + 8] = *(const uint4*)(src + 8);
    *(uint4*)&Kb[srow][sd + 16] = *(const uint4*)(src + 16);
    *(uint4*)&Kb[srow][sd + 24] = *(const uint4*)(src + 24);
  }
  __syncthreads();

  short8 af[4];
#pragma unroll
  for (int k0 = 0; k0 < 4; ++k0) af[k0] = *(const short8*)&Kb[w * 16 + lr][k0 * 32 + lg * 8];

  float best[4] = {1e30f, 1e30f, 1e30f, 1e30f};
  int bidx[4] = {0, 0, 0, 0};

  for (int cc = 0; cc < 8; ++cc) {
    __syncthreads();
    {
      const ushort* src = cb_bf + ((size_t)(h * nC + cc * 64 + srow)) * 128 + sd;
      *(uint4*)&Cb[srow][sd] = *(const uint4*)src;
      *(uint4*)&Cb[srow][sd + 8] = *(const uint4*)(src + 8);
      *(uint4*)&Cb[srow][sd + 16] = *(const uint4*)(src + 16);
      *(uint4*)&Cb[srow][sd + 24] = *(const uint4*)(src + 24);
      if (tid < 64) cnsh[tid] = cbn[h * nC + cc * 64 + tid];
    }
    __syncthreads();
#pragma unroll
    for (int ct = 0; ct < 4; ++ct) {
      f32x4 z = (f32x4){0.f, 0.f, 0.f, 0.f};
#pragma unroll
      for (int k0 = 0; k0 < 4; ++k0) {
        short8 cf = *(const short8*)&Cb[ct * 16 + lr][k0 * 32 + lg * 8];
        z = __builtin_amdgcn_mfma_f32_16x16x32_bf16(af[k0], cf, z, 0, 0, 0);
      }
      const int code = cc * 64 + ct * 16 + lr;
      const float cn = cnsh[ct * 16 + lr];
#pragma unroll
      for (int r2 = 0; r2 < 4; ++r2) {
        float d = cn - 2.f * z[r2];
        if (d < best[r2]) { best[r2] = d; bidx[r2] = code; }
      }
    }
  }

#pragma unroll
  for (int off = 1; off < 16; off <<= 1) {
#pragma unroll
    for (int r2 = 0; r2 < 4; ++r2) {
      float od = __shfl_xor(best[r2], off);
      int oi = __shfl_xor(bidx[r2], off);
      if (od < best[r2] || (od == best[r2] && oi < bidx[r2])) { best[r2] = od; bidx[r2] = oi; }
    }
  }
  if (lr == 0) {
#pragma unroll
    for (int r2 = 0; r2 < 4; ++r2) {
      int row = w * 16 + lg * 4 + r2;
      zsh[row] = bidx[r2];
      dsh[row] = best[r2];
    }
  }
  __syncthreads();

  {
    const int row = tid >> 2, part = (tid & 3) * 32;
    const ushort* src = cb_bf + ((size_t)(h * nC + zsh[row])) * 128 + part;
    ushort* dst = khat_bf + ((size_t)((b * nT + t0 + row) * nH + h)) * 128 + part;
    *(uint4*)dst = *(const uint4*)src;
    *(uint4*)(dst + 8) = *(const uint4*)(src + 8);
    *(uint4*)(dst + 16) = *(const uint4*)(src + 16);
    *(uint4*)(dst + 24) = *(const uint4*)(src + 24);
  }

  if (tid < 64) {
    float s = mask[b * nT + t0 + tid] *
              (knorm2[(size_t)(b * nT + t0 + tid) * nH + h] + dsh[tid]);
#pragma unroll
    for (int off = 32; off; off >>= 1) s += __shfl_down(s, off);
    if (tid == 0) blocksq[blockIdx.y * gridDim.x + blockIdx.x] = s;
  }
}

// ---------------- MFMA flash attention (R13/R15 sync structure) ----------------
// grid = (bh, t0/64): linear id % 8 = h -> same-(b,h) blocks co-resident on one XCD.
__global__ __launch_bounds__(256) void attn_mfma_kernel(
    const ushort* __restrict__ qb, const ushort* __restrict__ khat,
    const ushort* __restrict__ vbuf, const ushort* __restrict__ xlk,
    const ushort* __restrict__ xlv, const ushort* __restrict__ cbb,
    const ushort* __restrict__ aggU, const float* __restrict__ aggL,
    const ushort* __restrict__ gbuf, ushort* __restrict__ o) {
  __shared__ ushort Ks[64][136];
  __shared__ ushort Vts[128][72];
  __shared__ ushort Ps[4][16][72];
  __shared__ float lowb[64];

  const int tid = threadIdx.x;
  const int w = tid >> 6, l = tid & 63;
  const int lr = l & 15, lg = l >> 4;
  const int b = blockIdx.x >> 3, h = blockIdx.x & 7;
  const int t0 = blockIdx.y * 64;

  short8 qf[4];
  {
    const ushort* qrow = qb + ((size_t)((b * nT + t0 + w * 16 + lr) * nH + h)) * 128;
#pragma unroll
    for (int k0 = 0; k0 < 4; ++k0) qf[k0] = *(const short8*)(qrow + k0 * 32 + lg * 8);
  }

  float m_r[4] = {-1e30f, -1e30f, -1e30f, -1e30f};
  float l_r[4] = {0.f, 0.f, 0.f, 0.f};
  f32x4 acc_o[8];
#pragma unroll
  for (int dt = 0; dt < 8; ++dt) acc_o[dt] = (f32x4){0.f, 0.f, 0.f, 0.f};

  const int srow = tid >> 2, sd = (tid & 3) * 32;
  const int kp = tid & 31, dbase = (tid >> 5) * 16;

  auto stageK = [&](const ushort* src) {
#pragma unroll
    for (int q4 = 0; q4 < 4; ++q4)
      *(uint4*)&Ks[srow][sd + q4 * 8] = *(const uint4*)(src + q4 * 8);
  };
  auto stageVbf = [&](const ushort* v0, const ushort* v1) {
    short8 a0 = *(const short8*)(v0);
    short8 a1 = *(const short8*)(v0 + 8);
    short8 b0 = *(const short8*)(v1);
    short8 b1 = *(const short8*)(v1 + 8);
#pragma unroll
    for (int i2 = 0; i2 < 8; ++i2) {
      *(uint*)&Vts[dbase + i2][2 * kp] = (uint)(ushort)a0[i2] | ((uint)(ushort)b0[i2] << 16);
      *(uint*)&Vts[dbase + 8 + i2][2 * kp] = (uint)(ushort)a1[i2] | ((uint)(ushort)b1[i2] << 16);
    }
  };

  auto chunk_body = [&](int sbase, bool AGG, bool MASKQ) {
    f32x4 sc[4];
    __builtin_amdgcn_s_setprio(1);
#pragma unroll
    for (int kt = 0; kt < 4; ++kt) {
      f32x4 z = (f32x4){0.f, 0.f, 0.f, 0.f};
#pragma unroll
      for (int k0 = 0; k0 < 4; ++k0) {
        short8 kf = *(const short8*)&Ks[kt * 16 + lr][k0 * 32 + lg * 8];
        z = __builtin_amdgcn_mfma_f32_16x16x32_bf16(qf[k0], kf, z, 0, 0, 0);
      }
      sc[kt] = z;
    }
    __builtin_amdgcn_s_setprio(0);
    float sv[4][4];
    float pm[4] = {-1e30f, -1e30f, -1e30f, -1e30f};
#pragma unroll
    for (int kt = 0; kt < 4; ++kt)
#pragma unroll
      for (int r2 = 0; r2 < 4; ++r2) {
        float s = sc[kt][r2] * RTAU;
        if (MASKQ) {
          int key = sbase + kt * 16 + lr;
          int tl = t0 + w * 16 + lg * 4 + r2 + nM;
          if (key > tl) s = -1e30f;
        }
        sv[kt][r2] = s;
        pm[r2] = fmaxf(pm[r2], s);
      }
#pragma unroll
    for (int r2 = 0; r2 < 4; ++r2)
#pragma unroll
      for (int off = 1; off < 16; off <<= 1) pm[r2] = fmaxf(pm[r2], __shfl_xor(pm[r2], off));
    float scale[4], rs[4];
#pragma unroll
    for (int r2 = 0; r2 < 4; ++r2) {
      float mn = fmaxf(m_r[r2], pm[r2]);
      scale[r2] = __expf(m_r[r2] - mn);
      m_r[r2] = mn;
      rs[r2] = 0.f;
    }
#pragma unroll
    for (int kt = 0; kt < 4; ++kt)
#pragma unroll
      for (int r2 = 0; r2 < 4; ++r2) {
        float p = __expf(sv[kt][r2] - m_r[r2]);
        rs[r2] += AGG ? p * lowb[kt * 16 + lr] : p;
        Ps[w][lg * 4 + r2][kt * 16 + lr] = f2bf(p);
      }
#pragma unroll
    for (int r2 = 0; r2 < 4; ++r2)
#pragma unroll
      for (int off = 1; off < 16; off <<= 1) rs[r2] += __shfl_xor(rs[r2], off);
#pragma unroll
    for (int r2 = 0; r2 < 4; ++r2) l_r[r2] = l_r[r2] * scale[r2] + rs[r2];
#pragma unroll
    for (int dt = 0; dt < 8; ++dt)
#pragma unroll
      for (int r2 = 0; r2 < 4; ++r2) acc_o[dt][r2] *= scale[r2];
    short8 pa0 = *(const short8*)&Ps[w][lr][lg * 8];
    short8 pa1 = *(const short8*)&Ps[w][lr][32 + lg * 8];
    __builtin_amdgcn_s_setprio(1);
#pragma unroll
    for (int dt = 0; dt < 8; ++dt) {
      short8 vf0 = *(const short8*)&Vts[dt * 16 + lr][lg * 8];
      short8 vf1 = *(const short8*)&Vts[dt * 16 + lr][32 + lg * 8];
      acc_o[dt] = __builtin_amdgcn_mfma_f32_16x16x32_bf16(pa0, vf0, acc_o[dt], 0, 0, 0);
      acc_o[dt] = __builtin_amdgcn_mfma_f32_16x16x32_bf16(pa1, vf1, acc_o[dt], 0, 0, 0);
    }
    __builtin_amdgcn_s_setprio(0);
  };

  const int nch = t0 / 64 + 9;
  for (int ci = 0; ci < nch; ++ci) {
    const int sbase = ci * 64;
    __syncthreads();
    {
      int s = sbase + srow;
      const ushort* src = (s < nM)
          ? xlk + ((size_t)(b * nH + h) * nM + s) * 128 + sd
          : khat + ((size_t)((b * nT + (s - nM)) * nH + h)) * 128 + sd;
      stageK(src);
    }
    {
      int s0 = sbase + 2 * kp;
      if (s0 < nM) {
        const ushort* v0 = xlv + ((size_t)(b * nH + h) * nM + s0) * 128 + dbase;
        stageVbf(v0, v0 + 128);
      } else {
        const ushort* v0 = vbuf + ((size_t)((b * nT + (s0 - nM)) * nH + h)) * 128 + dbase;
        stageVbf(v0, v0 + nH * 128);
      }
    }
    __syncthreads();
    chunk_body(sbase, false, ci == nch - 1);
  }

  for (int ca = 0; ca < 8; ++ca) {
    const int sbase = ca * 64;
    __syncthreads();
    stageK(cbb + ((size_t)h * nC + sbase + srow) * 128 + sd);
    {
      const ushort* v0 = aggU + ((size_t)(b * nH + h) * nC + sbase + 2 * kp) * 128 + dbase;
      stageVbf(v0, v0 + 128);
    }
    if (tid < 64) lowb[tid] = aggL[(size_t)(b * nH + h) * nC + sbase + tid];
    __syncthreads();
    chunk_body(sbase, true, false);
  }

  float inv[4];
#pragma unroll
  for (int r2 = 0; r2 < 4; ++r2) inv[r2] = 1.f / l_r[r2];
#pragma unroll
  for (int dt = 0; dt < 8; ++dt)
#pragma unroll
    for (int r2 = 0; r2 < 4; ++r2) {
      int trow = t0 + w * 16 + lg * 4 + r2;
      size_t oi = ((size_t)(b * nT + trow)) * nD + h * 128 + dt * 16 + lr;
      float gv = bf2f(gbuf[oi]);
      o[oi] = f2bf(acc_o[dt][r2] * inv[r2] * gv);
    }
}

// ---------------- losses ----------------
__global__ __launch_bounds__(256) void finalize_kernel(const float* __restrict__ blocksq,
                                                       int nblk,
                                                       const float* __restrict__ mask,
                                                       float* __restrict__ outp) {
  __shared__ float sm[8];
  const int tid = threadIdx.x;
  float s = 0.f, ms = 0.f;
  for (int i = tid; i < NROW; i += 256) {
    if (i < nblk) s += blocksq[i];
    ms += mask[i];
  }
#pragma unroll
  for (int off = 32; off; off >>= 1) { s += __shfl_down(s, off); ms += __shfl_down(ms, off); }
  if ((tid & 63) == 0) { sm[tid >> 6] = s; sm[4 + (tid >> 6)] = ms; }
  __syncthreads();
  if (tid == 0) {
    float ts = sm[0] + sm[1] + sm[2] + sm[3];
    float tm = sm[4] + sm[5] + sm[6] + sm[7];
    float l = ts / (tm * (float)nH + 1e-6f);
    outp[0] = l;
    outp[1] = l;
  }
}

}  // namespace

extern "C" void kernel_launch(void* const* d_in, const int* in_sizes, int n_in,
                              void* d_out, int out_size, void* d_ws, size_t ws_size,
                              hipStream_t stream) {
  const float* x    = (const float*)d_in[0];
  const float* mask = (const float*)d_in[2];
  const float* xlk  = (const float*)d_in[3];
  const float* xlv  = (const float*)d_in[4];
  const float* aggU = (const float*)d_in[5];
  const float* aggL = (const float*)d_in[6];
  const float* wlng = (const float*)d_in[7];
  const float* wlnb = (const float*)d_in[8];
  const float* wq   = (const float*)d_in[9];
  const float* wk   = (const float*)d_in[10];
  const float* wv   = (const float*)d_in[11];
  const float* wg   = (const float*)d_in[12];
  const float* wres = (const float*)d_in[13];
  const float* xu   = (const float*)d_in[14];
  const float* cb   = (const float*)d_in[15];
  float* out = (float*)d_out;

  float* ws = (float*)d_ws;
  const size_t SZ = (size_t)NROW * nD;   // 4,194,304
  float*  kregion = ws;                                    // SZ floats: kbf lives here
  ushort* qbuf_bf = (ushort*)(ws + SZ);                    // SZ ushorts
  ushort* khat_bf = (ushort*)(ws + SZ + SZ / 2);           // SZ ushorts
  ushort* vbuf_bf = (ushort*)(ws + 2 * SZ);                // SZ ushorts
  ushort* gbuf_bf = (ushort*)(ws + 2 * SZ + SZ / 2);       // SZ ushorts
  ushort* xt_bf   = (ushort*)(ws + 3 * SZ);                // SZ ushorts (obuf overlay)
  ushort* wqkvg_t = (ushort*)(ws + 3 * SZ + SZ / 2);       // SZ ushorts
  ushort* wres_t  = (ushort*)(ws + 4 * SZ);                // 1M ushorts
  ushort* xlk_bf  = (ushort*)(ws + 4 * SZ + SZ / 8);       // SZ ushorts
  ushort* xlv_bf  = (ushort*)(ws + 4 * SZ + SZ / 8 + SZ / 2);
  ushort* aggU_bf = (ushort*)(ws + 4 * SZ + SZ / 8 + SZ);
  ushort* cb_bf   = (ushort*)(ws + 4 * SZ + SZ / 8 + 3 * SZ / 2);
  float*  cbn     = ws + 4 * SZ + SZ / 8 + 3 * SZ / 2 + SZ / 16;
  float*  knorm2  = cbn + 4096;
  float*  bsq     = knorm2 + 32768;
  ushort* kbf     = (ushort*)kregion;   // NOT xt_bf: GEMM reads xt while writing kbf
  ushort* obuf_bf = xt_bf;              // xt dead after qkvg GEMM

  prep_kernel<<<PREP_CB, 256, 0, stream>>>(
      x, wlng, wlnb, xt_bf, xlk, xlk_bf, xlv, xlv_bf, aggU, aggU_bf,
      wq, wk, wv, wg, wres, wqkvg_t, wres_t, cb, cbn, cb_bf);

  // fused q|k|v|g projection + headwise LN epilogue (q: +xu; k: bf16 + knorm2)
  gemm_bf16_kernel<1><<<dim3(32, 32), 256, 0, stream>>>(
      xt_bf, wqkvg_t, nullptr, qbuf_bf, vbuf_bf, gbuf_bf, kbf, knorm2, xu);

  vq_mfma_kernel<<<dim3(nT / 64, nB * nH), 256, 0, stream>>>(kbf, cb_bf, cbn, knorm2,
                                                             mask, khat_bf, bsq);

  attn_mfma_kernel<<<dim3(nB * nH, nT / 64), 256, 0, stream>>>(
      qbuf_bf, khat_bf, vbuf_bf, xlk_bf, xlv_bf, cb_bf, aggU_bf, aggL, gbuf_bf, obuf_bf);

  gemm_bf16_kernel<0><<<dim3(8, 32), 256, 0, stream>>>(
      obuf_bf, wres_t, out, nullptr, nullptr, nullptr, nullptr, nullptr, nullptr);
  finalize_kernel<<<1, 256, 0, stream>>>(bsq, nT / 64 * nB * nH, mask, out + SZ);
}

// Round 24
// 217.059 us; speedup vs baseline: 1.2692x; 1.0106x over previous
//
#include <hip/hip_runtime.h>
#include <math.h>

namespace {

constexpr int nB = 8, nT = 512, nD = 1024, nH = 8, nDK = 128, nDV = 128, nC = 512, nM = 512;
constexpr int NROW = nB * nT;                  // 4096
constexpr float RTAU = 0.08838834764831845f;   // 1/sqrt(128)

typedef __attribute__((ext_vector_type(8))) short short8;
typedef __attribute__((ext_vector_type(4))) float f32x4;

__device__ __forceinline__ ushort f2bf(float f) {
  union { float f; uint u; } x; x.f = f;
  uint r = x.u + 0x7fff + ((x.u >> 16) & 1);
  return (ushort)(r >> 16);
}
__device__ __forceinline__ uint pk2(float a, float b) {
  return (uint)f2bf(a) | ((uint)f2bf(b) << 16);
}
__device__ __forceinline__ float bf2f(ushort u) {
  return __uint_as_float(((uint)u) << 16);
}
__device__ __forceinline__ void gload16(const void* g, void* l) {
  __builtin_amdgcn_global_load_lds((const __attribute__((address_space(1))) void*)g,
                                   (__attribute__((address_space(3))) void*)l, 16, 0, 0);
}

// ---------------- fused prep: ln | tobf x3 | wtrans x5 | cbprep ----------------
constexpr int PREP_LN = 4096;
constexpr int PREP_CAST = PREP_LN + 12288;   // 16384
constexpr int PREP_WT = PREP_CAST + 1280;    // 17664
constexpr int PREP_CB = PREP_WT + 2048;      // 19712

__global__ __launch_bounds__(256) void prep_kernel(
    const float* __restrict__ x, const float* __restrict__ gw, const float* __restrict__ bw,
    ushort* __restrict__ xt_bf,
    const float* __restrict__ xlk, ushort* __restrict__ xlk_bf,
    const float* __restrict__ xlv, ushort* __restrict__ xlv_bf,
    const float* __restrict__ aggU, ushort* __restrict__ aggU_bf,
    const float* __restrict__ wq, const float* __restrict__ wk, const float* __restrict__ wv,
    const float* __restrict__ wg, const float* __restrict__ wres,
    ushort* __restrict__ wqkvg_t, ushort* __restrict__ wres_t,
    const float* __restrict__ cb, float* __restrict__ cbn, ushort* __restrict__ cb_bf) {
  __shared__ float tile[64][65];
  __shared__ float smc[4];
  const int bid = blockIdx.x;
  const int tid = threadIdx.x;

  if (bid < PREP_LN) {
    size_t row = bid;
    float4 v = ((const float4*)(x + row * nD))[tid];
    {
      int lane = tid & 63, w = tid >> 6;
      float s = v.x + v.y + v.z + v.w;
#pragma unroll
      for (int off = 32; off; off >>= 1) s += __shfl_down(s, off);
      if (lane == 0) smc[w] = s;
    }
    __syncthreads();
    float mu = (smc[0] + smc[1] + smc[2] + smc[3]) * (1.f / nD);
    __syncthreads();
    float4 d = make_float4(v.x - mu, v.y - mu, v.z - mu, v.w - mu);
    {
      int lane = tid & 63, w = tid >> 6;
      float s = d.x * d.x + d.y * d.y + d.z * d.z + d.w * d.w;
#pragma unroll
      for (int off = 32; off; off >>= 1) s += __shfl_down(s, off);
      if (lane == 0) smc[w] = s;
    }
    __syncthreads();
    float var = (smc[0] + smc[1] + smc[2] + smc[3]) * (1.f / nD);
    float rs = rsqrtf(var + 1e-6f);
    float4 gg = ((const float4*)gw)[tid];
    float4 bb = ((const float4*)bw)[tid];
    uint2 pb;
    pb.x = pk2(d.x * rs * gg.x + bb.x, d.y * rs * gg.y + bb.y);
    pb.y = pk2(d.z * rs * gg.z + bb.z, d.w * rs * gg.w + bb.w);
    ((uint2*)(xt_bf + row * nD))[tid] = pb;
  } else if (bid < PREP_CAST) {
    const int i = bid - PREP_LN;
    const int which = i >> 12, blk = i & 4095;
    const float* src = which == 0 ? xlk : (which == 1 ? xlv : aggU);
    ushort* dst = which == 0 ? xlk_bf : (which == 1 ? xlv_bf : aggU_bf);
    size_t idx = (size_t)blk * 256 + tid;
    float4 v = ((const float4*)src)[idx];
    uint2 p;
    p.x = pk2(v.x, v.y);
    p.y = pk2(v.z, v.w);
    ((uint2*)dst)[idx] = p;
  } else if (bid < PREP_WT) {
    const int i = bid - PREP_CAST;
    const int z = i >> 8, rem = i & 255;
    const int kz = (rem >> 4) * 64, nz = (rem & 15) * 64;
    const float* W;
    ushort* D;
    if (z == 0)      { W = wq;   D = wqkvg_t; }
    else if (z == 1) { W = wk;   D = wqkvg_t + (size_t)1024 * 1024; }
    else if (z == 2) { W = wv;   D = wqkvg_t + (size_t)2048 * 1024; }
    else if (z == 3) { W = wg;   D = wqkvg_t + (size_t)3072 * 1024; }
    else             { W = wres; D = wres_t; }
    const int c = tid & 63, r4 = tid >> 6;
#pragma unroll
    for (int k = 0; k < 16; ++k) {
      int r = k * 4 + r4;
      tile[r][c] = W[(size_t)(kz + r) * 1024 + nz + c];
    }
    __syncthreads();
#pragma unroll
    for (int k = 0; k < 16; ++k) {
      int n = k * 4 + r4;
      D[(size_t)(nz + n) * 1024 + kz + c] = f2bf(tile[c][n]);
    }
  } else {
    const int i = bid - PREP_WT;
    const int grp = tid >> 7, t128 = tid & 127;
    const int hc = i * 2 + grp;
    float v = cb[(size_t)hc * 128 + t128];
    cb_bf[(size_t)hc * 128 + t128] = f2bf(v);
    float s = v * v;
#pragma unroll
    for (int off = 32; off; off >>= 1) s += __shfl_down(s, off);
    if ((t128 & 63) == 0) smc[grp * 2 + (t128 >> 6)] = s;
    __syncthreads();
    if (t128 == 0) cbn[hc] = smc[grp * 2] + smc[grp * 2 + 1];
  }
}

// ---------------- bf16 MFMA GEMM (128x128 tile, BK=64, XOR-swizzled LDS) ----------------
template <int MODE>
__global__ __launch_bounds__(256) void gemm_bf16_kernel(const ushort* __restrict__ A,
                                                        const ushort* __restrict__ Bt,
                                                        float* __restrict__ C0,
                                                        ushort* __restrict__ C1,
                                                        ushort* __restrict__ C2,
                                                        ushort* __restrict__ C3,
                                                        ushort* __restrict__ kbf,
                                                        float* __restrict__ knorm2,
                                                        const float* __restrict__ xu) {
  __shared__ __align__(16) ushort As[128 * 64];
  __shared__ __align__(16) ushort Bs[128 * 64];
  __shared__ float rowsum[128][2];
  __shared__ float rowsum2[128][2];
  const int tid = threadIdx.x;
  const int w = tid >> 6, l = tid & 63;
  const int lr = l & 15, lg = l >> 4;
  const int wr = w >> 1, wc = w & 1;
  const int n0 = blockIdx.x * 128;
  const int m0 = blockIdx.y * 128;
  constexpr int K = 1024;

  f32x4 acc[4][4];
#pragma unroll
  for (int i = 0; i < 4; ++i)
#pragma unroll
    for (int j = 0; j < 4; ++j) acc[i][j] = (f32x4){0.f, 0.f, 0.f, 0.f};

  // staging: [128][64] tile, 4 rounds x 256 thr x 8 elems (16B)
  const int eb = w * 512 + l * 8;
  int rowA[4], sof[4], eo[4];
#pragma unroll
  for (int r = 0; r < 4; ++r) {
    int e = r * 2048 + eb;
    rowA[r] = e >> 6;
    eo[r] = e * 2;                               // linear LDS byte offset
    sof[r] = ((e & 63) * 2) ^ ((rowA[r] & 7) << 4);  // swizzled source byte offset
  }

  for (int k0 = 0; k0 < K; k0 += 64) {
    __syncthreads();
#pragma unroll
    for (int r = 0; r < 4; ++r) {
      gload16((const char*)(A + (size_t)(m0 + rowA[r]) * K + k0) + sof[r], (char*)As + eo[r]);
      gload16((const char*)(Bt + (size_t)(n0 + rowA[r]) * K + k0) + sof[r], (char*)Bs + eo[r]);
    }
    __syncthreads();
#pragma unroll
    for (int kk = 0; kk < 2; ++kk) {
      short8 af[4], bfr[4];
#pragma unroll
      for (int i = 0; i < 4; ++i) {
        const int row = wr * 64 + i * 16 + lr;
        af[i] = *(const short8*)((const char*)As + row * 128 +
                                 ((kk * 64 + lg * 16) ^ ((row & 7) << 4)));
      }
#pragma unroll
      for (int j = 0; j < 4; ++j) {
        const int row = wc * 64 + j * 16 + lr;
        bfr[j] = *(const short8*)((const char*)Bs + row * 128 +
                                  ((kk * 64 + lg * 16) ^ ((row & 7) << 4)));
      }
      __builtin_amdgcn_s_setprio(1);
#pragma unroll
      for (int i = 0; i < 4; ++i)
#pragma unroll
        for (int j = 0; j < 4; ++j)
          acc[i][j] = __builtin_amdgcn_mfma_f32_16x16x32_bf16(af[i], bfr[j], acc[i][j], 0, 0, 0);
      __builtin_amdgcn_s_setprio(0);
    }
  }

  const int seg = n0 >> 10;
  const int nbase = n0 & 1023;
  if (MODE == 1 && seg <= 1) {
    const int h = nbase >> 7;
    float ps[4][4], ps2[4][4];
#pragma unroll
    for (int i = 0; i < 4; ++i)
#pragma unroll
      for (int r2 = 0; r2 < 4; ++r2) {
        float s = 0.f, s2 = 0.f;
#pragma unroll
        for (int j = 0; j < 4; ++j) {
          float v = acc[i][j][r2];
          s += v;
          s2 += v * v;
        }
#pragma unroll
        for (int off = 1; off < 16; off <<= 1) {
          s += __shfl_xor(s, off);
          s2 += __shfl_xor(s2, off);
        }
        ps[i][r2] = s;
        ps2[i][r2] = s2;
      }
    if (lr == 0) {
#pragma unroll
      for (int i = 0; i < 4; ++i)
#pragma unroll
        for (int r2 = 0; r2 < 4; ++r2) {
          int rloc = wr * 64 + i * 16 + lg * 4 + r2;
          rowsum[rloc][wc] = ps[i][r2];
          rowsum2[rloc][wc] = ps2[i][r2];
        }
    }
    __syncthreads();
#pragma unroll
    for (int i = 0; i < 4; ++i)
#pragma unroll
      for (int r2 = 0; r2 < 4; ++r2) {
        const int rloc = wr * 64 + i * 16 + lg * 4 + r2;
        const int grow = m0 + rloc;
        float tot = rowsum[rloc][0] + rowsum[rloc][1];
        float tot2 = rowsum2[rloc][0] + rowsum2[rloc][1];
        float mu = tot * (1.f / 128.f);
        float qf = tot2 - 128.f * mu * mu;
        float rs = rsqrtf(qf * (1.f / 128.f) + 1e-6f);
#pragma unroll
        for (int j = 0; j < 4; ++j) {
          const int col = wc * 64 + j * 16 + lr;
          float v = (acc[i][j][r2] - mu) * rs;
          if (seg == 0) {
            v += xu[h * 128 + col];
            C1[(size_t)grow * 1024 + nbase + col] = f2bf(v);
          } else {
            kbf[(size_t)grow * 1024 + nbase + col] = f2bf(v);
          }
        }
        if (seg == 1 && lr == 0 && wc == 0) knorm2[(size_t)grow * 8 + h] = qf * rs * rs;
      }
  } else {
#pragma unroll
    for (int i = 0; i < 4; ++i)
#pragma unroll
      for (int j = 0; j < 4; ++j)
#pragma unroll
        for (int r2 = 0; r2 < 4; ++r2) {
          const int row = m0 + wr * 64 + i * 16 + lg * 4 + r2;
          const int col = wc * 64 + j * 16 + lr;
          float v = acc[i][j][r2];
          if (MODE == 0) {
            C0[(size_t)row * 1024 + n0 + col] = v;
          } else {
            const int nloc = nbase + col;
            if (seg == 2) {
              C2[(size_t)row * 1024 + nloc] = f2bf(v);
            } else {
              float s = v / (1.f + __expf(-v));
              C3[(size_t)row * 1024 + nloc] = f2bf(s);
            }
          }
        }
  }
}

// ---------------- MFMA VQ: argmin over 512 codes via k.c MFMA ----------------
__global__ __launch_bounds__(256) void vq_mfma_kernel(const ushort* __restrict__ kbf,
                                                      const ushort* __restrict__ cb_bf,
                                                      const float* __restrict__ cbn,
                                                      const float* __restrict__ knorm2,
                                                      const float* __restrict__ mask,
                                                      ushort* __restrict__ khat_bf,
                                                      float* __restrict__ blocksq) {
  __shared__ ushort Kb[64][136];
  __shared__ ushort Cb[64][136];
  __shared__ float cnsh[64];
  __shared__ int zsh[64];
  __shared__ float dsh[64];
  const int tid = threadIdx.x;
  const int w = tid >> 6, l = tid & 63;
  const int lr = l & 15, lg = l >> 4;
  const int b = blockIdx.y >> 3, h = blockIdx.y & 7;
  const int t0 = blockIdx.x * 64;
  const int srow = tid >> 2, sd = (tid & 3) * 32;

  {
    const ushort* src = kbf + ((size_t)((b * nT + t0 + srow) * nH + h)) * 128 + sd;
    *(uint4*)&Kb[srow][sd] = *(const uint4*)src;
    *(uint4*)&Kb[srow][sd + 8] = *(const uint4*)(src + 8);
    *(uint4*)&Kb[srow][sd + 16] = *(const uint4*)(src + 16);
    *(uint4*)&Kb[srow][sd + 24] = *(const uint4*)(src + 24);
  }
  __syncthreads();

  short8 af[4];
#pragma unroll
  for (int k0 = 0; k0 < 4; ++k0) af[k0] = *(const short8*)&Kb[w * 16 + lr][k0 * 32 + lg * 8];

  float best[4] = {1e30f, 1e30f, 1e30f, 1e30f};
  int bidx[4] = {0, 0, 0, 0};

  for (int cc = 0; cc < 8; ++cc) {
    __syncthreads();
    {
      const ushort* src = cb_bf + ((size_t)(h * nC + cc * 64 + srow)) * 128 + sd;
      *(uint4*)&Cb[srow][sd] = *(const uint4*)src;
      *(uint4*)&Cb[srow][sd + 8] = *(const uint4*)(src + 8);
      *(uint4*)&Cb[srow][sd + 16] = *(const uint4*)(src + 16);
      *(uint4*)&Cb[srow][sd + 24] = *(const uint4*)(src + 24);
      if (tid < 64) cnsh[tid] = cbn[h * nC + cc * 64 + tid];
    }
    __syncthreads();
#pragma unroll
    for (int ct = 0; ct < 4; ++ct) {
      f32x4 z = (f32x4){0.f, 0.f, 0.f, 0.f};
#pragma unroll
      for (int k0 = 0; k0 < 4; ++k0) {
        short8 cf = *(const short8*)&Cb[ct * 16 + lr][k0 * 32 + lg * 8];
        z = __builtin_amdgcn_mfma_f32_16x16x32_bf16(af[k0], cf, z, 0, 0, 0);
      }
      const int code = cc * 64 + ct * 16 + lr;
      const float cn = cnsh[ct * 16 + lr];
#pragma unroll
      for (int r2 = 0; r2 < 4; ++r2) {
        float d = cn - 2.f * z[r2];
        if (d < best[r2]) { best[r2] = d; bidx[r2] = code; }
      }
    }
  }

#pragma unroll
  for (int off = 1; off < 16; off <<= 1) {
#pragma unroll
    for (int r2 = 0; r2 < 4; ++r2) {
      float od = __shfl_xor(best[r2], off);
      int oi = __shfl_xor(bidx[r2], off);
      if (od < best[r2] || (od == best[r2] && oi < bidx[r2])) { best[r2] = od; bidx[r2] = oi; }
    }
  }
  if (lr == 0) {
#pragma unroll
    for (int r2 = 0; r2 < 4; ++r2) {
      int row = w * 16 + lg * 4 + r2;
      zsh[row] = bidx[r2];
      dsh[row] = best[r2];
    }
  }
  __syncthreads();

  {
    const int row = tid >> 2, part = (tid & 3) * 32;
    const ushort* src = cb_bf + ((size_t)(h * nC + zsh[row])) * 128 + part;
    ushort* dst = khat_bf + ((size_t)((b * nT + t0 + row) * nH + h)) * 128 + part;
    *(uint4*)dst = *(const uint4*)src;
    *(uint4*)(dst + 8) = *(const uint4*)(src + 8);
    *(uint4*)(dst + 16) = *(const uint4*)(src + 16);
    *(uint4*)(dst + 24) = *(const uint4*)(src + 24);
  }

  if (tid < 64) {
    float s = mask[b * nT + t0 + tid] *
              (knorm2[(size_t)(b * nT + t0 + tid) * nH + h] + dsh[tid]);
#pragma unroll
    for (int off = 32; off; off >>= 1) s += __shfl_down(s, off);
    if (tid == 0) blocksq[blockIdx.y * gridDim.x + blockIdx.x] = s;
  }
}

// ---------------- MFMA flash attention (sync structure, XOR-swizzled LDS) ----------------
// grid = (bh, t0/64): linear id % 8 = h -> same-(b,h) blocks co-resident on one XCD.
// Ks[64][128], Vts[128][64], Ps[4][16][64] linear strides + byte^((row&7)<<4) on write+read:
// kills the (lr+lg) bank-granule aliasing of the old padded layouts (7.05M conflict cycles).
__global__ __launch_bounds__(256) void attn_mfma_kernel(
    const ushort* __restrict__ qb, const ushort* __restrict__ khat,
    const ushort* __restrict__ vbuf, const ushort* __restrict__ xlk,
    const ushort* __restrict__ xlv, const ushort* __restrict__ cbb,
    const ushort* __restrict__ aggU, const float* __restrict__ aggL,
    const ushort* __restrict__ gbuf, ushort* __restrict__ o) {
  __shared__ __align__(16) ushort Ks[64][128];
  __shared__ __align__(16) ushort Vts[128][64];
  __shared__ __align__(16) ushort Ps[4][16][64];
  __shared__ float lowb[64];

  const int tid = threadIdx.x;
  const int w = tid >> 6, l = tid & 63;
  const int lr = l & 15, lg = l >> 4;
  const int b = blockIdx.x >> 3, h = blockIdx.x & 7;
  const int t0 = blockIdx.y * 64;

  short8 qf[4];
  {
    const ushort* qrow = qb + ((size_t)((b * nT + t0 + w * 16 + lr) * nH + h)) * 128;
#pragma unroll
    for (int k0 = 0; k0 < 4; ++k0) qf[k0] = *(const short8*)(qrow + k0 * 32 + lg * 8);
  }

  float m_r[4] = {-1e30f, -1e30f, -1e30f, -1e30f};
  float l_r[4] = {0.f, 0.f, 0.f, 0.f};
  f32x4 acc_o[8];
#pragma unroll
  for (int dt = 0; dt < 8; ++dt) acc_o[dt] = (f32x4){0.f, 0.f, 0.f, 0.f};

  const int srow = tid >> 2, sd4 = (tid & 3) * 64;   // K staging: 4 thr/row, 64B chunks
  const int kp = tid & 31, dbase = (tid >> 5) * 16;  // V staging

  auto stageK = [&](const ushort* src) {
    char* kb = (char*)Ks + srow * 256;
    const int swz = (srow & 7) << 4;
#pragma unroll
    for (int q4 = 0; q4 < 4; ++q4)
      *(uint4*)(kb + ((sd4 + q4 * 16) ^ swz)) = *(const uint4*)(src + q4 * 8);
  };
  auto stageVbf = [&](const ushort* v0, const ushort* v1) {
    short8 a0 = *(const short8*)(v0);
    short8 a1 = *(const short8*)(v0 + 8);
    short8 b0 = *(const short8*)(v1);
    short8 b1 = *(const short8*)(v1 + 8);
    char* vb = (char*)Vts;
#pragma unroll
    for (int i2 = 0; i2 < 8; ++i2) {
      const int r0 = dbase + i2, r1 = dbase + 8 + i2;
      *(uint*)(vb + r0 * 128 + ((kp * 4) ^ ((r0 & 7) << 4))) =
          (uint)(ushort)a0[i2] | ((uint)(ushort)b0[i2] << 16);
      *(uint*)(vb + r1 * 128 + ((kp * 4) ^ ((r1 & 7) << 4))) =
          (uint)(ushort)a1[i2] | ((uint)(ushort)b1[i2] << 16);
    }
  };

  auto chunk_body = [&](int sbase, bool AGG, bool MASKQ) {
    const int rswz = (lr & 7) << 4;
    f32x4 sc[4];
    __builtin_amdgcn_s_setprio(1);
#pragma unroll
    for (int kt = 0; kt < 4; ++kt) {
      f32x4 z = (f32x4){0.f, 0.f, 0.f, 0.f};
      const char* kb = (const char*)Ks + (kt * 16 + lr) * 256;
#pragma unroll
      for (int k0 = 0; k0 < 4; ++k0) {
        short8 kf = *(const short8*)(kb + ((k0 * 64 + lg * 16) ^ rswz));
        z = __builtin_amdgcn_mfma_f32_16x16x32_bf16(qf[k0], kf, z, 0, 0, 0);
      }
      sc[kt] = z;
    }
    __builtin_amdgcn_s_setprio(0);
    float sv[4][4];
    float pm[4] = {-1e30f, -1e30f, -1e30f, -1e30f};
#pragma unroll
    for (int kt = 0; kt < 4; ++kt)
#pragma unroll
      for (int r2 = 0; r2 < 4; ++r2) {
        float s = sc[kt][r2] * RTAU;
        if (MASKQ) {
          int key = sbase + kt * 16 + lr;
          int tl = t0 + w * 16 + lg * 4 + r2 + nM;
          if (key > tl) s = -1e30f;
        }
        sv[kt][r2] = s;
        pm[r2] = fmaxf(pm[r2], s);
      }
#pragma unroll
    for (int r2 = 0; r2 < 4; ++r2)
#pragma unroll
      for (int off = 1; off < 16; off <<= 1) pm[r2] = fmaxf(pm[r2], __shfl_xor(pm[r2], off));
    float scale[4], rs[4];
#pragma unroll
    for (int r2 = 0; r2 < 4; ++r2) {
      float mn = fmaxf(m_r[r2], pm[r2]);
      scale[r2] = __expf(m_r[r2] - mn);
      m_r[r2] = mn;
      rs[r2] = 0.f;
    }
    char* pbw = (char*)Ps + w * 2048;
#pragma unroll
    for (int kt = 0; kt < 4; ++kt)
#pragma unroll
      for (int r2 = 0; r2 < 4; ++r2) {
        float p = __expf(sv[kt][r2] - m_r[r2]);
        rs[r2] += AGG ? p * lowb[kt * 16 + lr] : p;
        const int prow = lg * 4 + r2;
        *(ushort*)(pbw + prow * 128 +
                   (((kt * 16 + lr) * 2) ^ ((prow & 7) << 4))) = f2bf(p);
      }
#pragma unroll
    for (int r2 = 0; r2 < 4; ++r2)
#pragma unroll
      for (int off = 1; off < 16; off <<= 1) rs[r2] += __shfl_xor(rs[r2], off);
#pragma unroll
    for (int r2 = 0; r2 < 4; ++r2) l_r[r2] = l_r[r2] * scale[r2] + rs[r2];
#pragma unroll
    for (int dt = 0; dt < 8; ++dt)
#pragma unroll
      for (int r2 = 0; r2 < 4; ++r2) acc_o[dt][r2] *= scale[r2];
    const char* pbr = (const char*)Ps + w * 2048 + lr * 128;
    short8 pa0 = *(const short8*)(pbr + ((lg * 16) ^ rswz));
    short8 pa1 = *(const short8*)(pbr + ((64 + lg * 16) ^ rswz));
    __builtin_amdgcn_s_setprio(1);
#pragma unroll
    for (int dt = 0; dt < 8; ++dt) {
      const char* vb = (const char*)Vts + (dt * 16 + lr) * 128;
      short8 vf0 = *(const short8*)(vb + ((lg * 16) ^ rswz));
      short8 vf1 = *(const short8*)(vb + ((64 + lg * 16) ^ rswz));
      acc_o[dt] = __builtin_amdgcn_mfma_f32_16x16x32_bf16(pa0, vf0, acc_o[dt], 0, 0, 0);
      acc_o[dt] = __builtin_amdgcn_mfma_f32_16x16x32_bf16(pa1, vf1, acc_o[dt], 0, 0, 0);
    }
    __builtin_amdgcn_s_setprio(0);
  };

  const int nch = t0 / 64 + 9;
  for (int ci = 0; ci < nch; ++ci) {
    const int sbase = ci * 64;
    __syncthreads();
    {
      int s = sbase + srow;
      const ushort* src = (s < nM)
          ? xlk + ((size_t)(b * nH + h) * nM + s) * 128 + (tid & 3) * 32
          : khat + ((size_t)((b * nT + (s - nM)) * nH + h)) * 128 + (tid & 3) * 32;
      stageK(src);
    }
    {
      int s0 = sbase + 2 * kp;
      if (s0 < nM) {
        const ushort* v0 = xlv + ((size_t)(b * nH + h) * nM + s0) * 128 + dbase;
        stageVbf(v0, v0 + 128);
      } else {
        const ushort* v0 = vbuf + ((size_t)((b * nT + (s0 - nM)) * nH + h)) * 128 + dbase;
        stageVbf(v0, v0 + nH * 128);
      }
    }
    __syncthreads();
    chunk_body(sbase, false, ci == nch - 1);
  }

  for (int ca = 0; ca < 8; ++ca) {
    const int sbase = ca * 64;
    __syncthreads();
    stageK(cbb + ((size_t)h * nC + sbase + srow) * 128 + (tid & 3) * 32);
    {
      const ushort* v0 = aggU + ((size_t)(b * nH + h) * nC + sbase + 2 * kp) * 128 + dbase;
      stageVbf(v0, v0 + 128);
    }
    if (tid < 64) lowb[tid] = aggL[(size_t)(b * nH + h) * nC + sbase + tid];
    __syncthreads();
    chunk_body(sbase, true, false);
  }

  float inv[4];
#pragma unroll
  for (int r2 = 0; r2 < 4; ++r2) inv[r2] = 1.f / l_r[r2];
#pragma unroll
  for (int dt = 0; dt < 8; ++dt)
#pragma unroll
    for (int r2 = 0; r2 < 4; ++r2) {
      int trow = t0 + w * 16 + lg * 4 + r2;
      size_t oi = ((size_t)(b * nT + trow)) * nD + h * 128 + dt * 16 + lr;
      float gv = bf2f(gbuf[oi]);
      o[oi] = f2bf(acc_o[dt][r2] * inv[r2] * gv);
    }
}

// ---------------- losses ----------------
__global__ __launch_bounds__(256) void finalize_kernel(const float* __restrict__ blocksq,
                                                       int nblk,
                                                       const float* __restrict__ mask,
                                                       float* __restrict__ outp) {
  __shared__ float sm[8];
  const int tid = threadIdx.x;
  float s = 0.f, ms = 0.f;
  for (int i = tid; i < NROW; i += 256) {
    if (i < nblk) s += blocksq[i];
    ms += mask[i];
  }
#pragma unroll
  for (int off = 32; off; off >>= 1) { s += __shfl_down(s, off); ms += __shfl_down(ms, off); }
  if ((tid & 63) == 0) { sm[tid >> 6] = s; sm[4 + (tid >> 6)] = ms; }
  __syncthreads();
  if (tid == 0) {
    float ts = sm[0] + sm[1] + sm[2] + sm[3];
    float tm = sm[4] + sm[5] + sm[6] + sm[7];
    float l = ts / (tm * (float)nH + 1e-6f);
    outp[0] = l;
    outp[1] = l;
  }
}

}  // namespace

extern "C" void kernel_launch(void* const* d_in, const int* in_sizes, int n_in,
                              void* d_out, int out_size, void* d_ws, size_t ws_size,
                              hipStream_t stream) {
  const float* x    = (const float*)d_in[0];
  const float* mask = (const float*)d_in[2];
  const float* xlk  = (const float*)d_in[3];
  const float* xlv  = (const float*)d_in[4];
  const float* aggU = (const float*)d_in[5];
  const float* aggL = (const float*)d_in[6];
  const float* wlng = (const float*)d_in[7];
  const float* wlnb = (const float*)d_in[8];
  const float* wq   = (const float*)d_in[9];
  const float* wk   = (const float*)d_in[10];
  const float* wv   = (const float*)d_in[11];
  const float* wg   = (const float*)d_in[12];
  const float* wres = (const float*)d_in[13];
  const float* xu   = (const float*)d_in[14];
  const float* cb   = (const float*)d_in[15];
  float* out = (float*)d_out;

  float* ws = (float*)d_ws;
  const size_t SZ = (size_t)NROW * nD;   // 4,194,304
  float*  kregion = ws;                                    // SZ floats: kbf lives here
  ushort* qbuf_bf = (ushort*)(ws + SZ);                    // SZ ushorts
  ushort* khat_bf = (ushort*)(ws + SZ + SZ / 2);           // SZ ushorts
  ushort* vbuf_bf = (ushort*)(ws + 2 * SZ);                // SZ ushorts
  ushort* gbuf_bf = (ushort*)(ws + 2 * SZ + SZ / 2);       // SZ ushorts
  ushort* xt_bf   = (ushort*)(ws + 3 * SZ);                // SZ ushorts (obuf overlay)
  ushort* wqkvg_t = (ushort*)(ws + 3 * SZ + SZ / 2);       // SZ ushorts
  ushort* wres_t  = (ushort*)(ws + 4 * SZ);                // 1M ushorts
  ushort* xlk_bf  = (ushort*)(ws + 4 * SZ + SZ / 8);       // SZ ushorts
  ushort* xlv_bf  = (ushort*)(ws + 4 * SZ + SZ / 8 + SZ / 2);
  ushort* aggU_bf = (ushort*)(ws + 4 * SZ + SZ / 8 + SZ);
  ushort* cb_bf   = (ushort*)(ws + 4 * SZ + SZ / 8 + 3 * SZ / 2);
  float*  cbn     = ws + 4 * SZ + SZ / 8 + 3 * SZ / 2 + SZ / 16;
  float*  knorm2  = cbn + 4096;
  float*  bsq     = knorm2 + 32768;
  ushort* kbf     = (ushort*)kregion;   // NOT xt_bf: GEMM reads xt while writing kbf
  ushort* obuf_bf = xt_bf;              // xt dead after qkvg GEMM

  prep_kernel<<<PREP_CB, 256, 0, stream>>>(
      x, wlng, wlnb, xt_bf, xlk, xlk_bf, xlv, xlv_bf, aggU, aggU_bf,
      wq, wk, wv, wg, wres, wqkvg_t, wres_t, cb, cbn, cb_bf);

  // fused q|k|v|g projection + headwise LN epilogue (q: +xu; k: bf16 + knorm2)
  gemm_bf16_kernel<1><<<dim3(32, 32), 256, 0, stream>>>(
      xt_bf, wqkvg_t, nullptr, qbuf_bf, vbuf_bf, gbuf_bf, kbf, knorm2, xu);

  vq_mfma_kernel<<<dim3(nT / 64, nB * nH), 256, 0, stream>>>(kbf, cb_bf, cbn, knorm2,
                                                             mask, khat_bf, bsq);

  attn_mfma_kernel<<<dim3(nB * nH, nT / 64), 256, 0, stream>>>(
      qbuf_bf, khat_bf, vbuf_bf, xlk_bf, xlv_bf, cb_bf, aggU_bf, aggL, gbuf_bf, obuf_bf);

  gemm_bf16_kernel<0><<<dim3(8, 32), 256, 0, stream>>>(
      obuf_bf, wres_t, out, nullptr, nullptr, nullptr, nullptr, nullptr, nullptr);
  finalize_kernel<<<1, 256, 0, stream>>>(bsq, nT / 64 * nB * nH, mask, out + SZ);
}